// Round 1
// baseline (945.701 us; speedup 1.0000x reference)
//
#include <hip/hip_runtime.h>
#include <cstdint>
#include <cstddef>

#define BATCH  4
#define RUNITS 128
#define CC     129            // 1 + RUNITS
#define MM     5              // 2*K+1
#define FDIM   (BATCH*CC)     // 516
#define KTOT   (MM*CC)        // 645

// ---------------- graph prep ----------------

__global__ void k_zero_i(int* p, int n) {
  int i = blockIdx.x*blockDim.x + threadIdx.x;
  if (i < n) p[i] = 0;
}

__global__ void k_deg_cnt(const int* __restrict__ src, const int* __restrict__ dst,
                          const float* __restrict__ w, int E,
                          float* deg_out, float* deg_in, int* cnt_f, int* cnt_b) {
  int e = blockIdx.x*blockDim.x + threadIdx.x;
  if (e >= E) return;
  int s = src[e], d = dst[e]; float we = w[e];
  atomicAdd(&deg_out[s], we);
  atomicAdd(&deg_in[d], we);
  atomicAdd(&cnt_f[s], 1);
  atomicAdd(&cnt_b[d], 1);
}

// block 0 scans cnt_f -> ptr_f/cur_f, block 1 scans cnt_b -> ptr_b/cur_b
__global__ __launch_bounds__(1024) void k_scan2(
    const int* __restrict__ cnt_f, int* ptr_f, int* cur_f,
    const int* __restrict__ cnt_b, int* ptr_b, int* cur_b, int n) {
  const int* cnt = (blockIdx.x == 0) ? cnt_f : cnt_b;
  int* ptr = (blockIdx.x == 0) ? ptr_f : ptr_b;
  int* cur = (blockIdx.x == 0) ? cur_f : cur_b;
  __shared__ int sm[1024];
  __shared__ int carry_s;
  int tid = threadIdx.x;
  if (tid == 0) carry_s = 0;
  __syncthreads();
  for (int base = 0; base < n; base += 1024) {
    int i = base + tid;
    int v = (i < n) ? cnt[i] : 0;
    sm[tid] = v;
    __syncthreads();
    int acc = v;
    for (int off = 1; off < 1024; off <<= 1) {
      int t = (tid >= off) ? sm[tid - off] : 0;
      __syncthreads();
      acc += t;
      sm[tid] = acc;
      __syncthreads();
    }
    int carry = carry_s;
    if (i < n) { ptr[i] = carry + acc - v; cur[i] = carry + acc - v; }
    __syncthreads();              // everyone read carry_s before update
    if (tid == 1023) carry_s = carry + sm[1023];
    __syncthreads();
  }
  if (tid == 0) ptr[n] = carry_s;
}

__global__ void k_fill(const int* __restrict__ src, const int* __restrict__ dst,
                       const float* __restrict__ w, int E,
                       const float* __restrict__ deg_out, const float* __restrict__ deg_in,
                       int* cur_f, int* cur_b,
                       int* col_f, float* val_f, int* col_b, float* val_b) {
  int e = blockIdx.x*blockDim.x + threadIdx.x;
  if (e >= E) return;
  int s = src[e], d = dst[e]; float we = w[e];
  int pf = atomicAdd(&cur_f[s], 1);
  col_f[pf] = d; val_f[pf] = we / deg_out[s];
  int pb = atomicAdd(&cur_b[d], 1);
  col_b[pb] = s; val_b[pb] = we / deg_in[d];
}

// ---------------- feature assembly ----------------

// x0[n*FDIM + b*CC + c] = (c==0) ? inputs[b*N+n] : hsrc[(b*N+n)*128 + c-1]
__global__ void k_build_x0(const float* __restrict__ inp, const float* __restrict__ hsrc,
                           float* __restrict__ x0, int N) {
  size_t idx = (size_t)blockIdx.x*blockDim.x + threadIdx.x;
  size_t total = (size_t)N*FDIM;
  if (idx >= total) return;
  int n = (int)(idx / FDIM);
  int rem = (int)(idx - (size_t)n*FDIM);
  int b = rem / CC, c = rem - b*CC;
  float v = (c == 0) ? inp[(size_t)b*N + n]
                     : hsrc[((size_t)b*N + n)*RUNITS + (c-1)];
  x0[idx] = v;
}

// Wp[(m*CC+c)*ncol + o] = W[(c*MM+m)*ncol + o]
__global__ void k_pack(const float* __restrict__ W, float* __restrict__ Wp, int ncol) {
  int idx = blockIdx.x*blockDim.x + threadIdx.x;
  int total = KTOT * ncol;
  if (idx >= total) return;
  int k = idx / ncol, o = idx - k*ncol;
  int m = k / CC, c = k - m*CC;
  Wp[idx] = W[(size_t)(c*MM + m)*ncol + o];
}

// ---------------- SPMM: out[n] = alpha * sum_e val*X[col] + beta*Y[n] ----------------

__global__ __launch_bounds__(256) void k_spmm(
    const int* __restrict__ ptr, const int* __restrict__ col, const float* __restrict__ val,
    const float* __restrict__ X, const float* __restrict__ Y, float* __restrict__ out,
    float alpha, float beta) {
  int n = blockIdx.x;
  int s = ptr[n], e = ptr[n+1];
  int t = threadIdx.x;
  float a0 = 0.f, a1 = 0.f, a2 = 0.f;
  bool h2 = (t + 512) < FDIM;
  for (int i = s; i < e; ++i) {
    int c = col[i];
    float v = val[i];
    const float* Xr = X + (size_t)c*FDIM;
    a0 += v * Xr[t];
    a1 += v * Xr[t+256];
    if (h2) a2 += v * Xr[t+512];
  }
  size_t base = (size_t)n*FDIM;
  float y0 = (beta != 0.f) ? beta*Y[base+t]     : 0.f;
  float y1 = (beta != 0.f) ? beta*Y[base+t+256] : 0.f;
  out[base+t]     = alpha*a0 + y0;
  out[base+t+256] = alpha*a1 + y1;
  if (h2) {
    float y2 = (beta != 0.f) ? beta*Y[base+t+512] : 0.f;
    out[base+t+512] = alpha*a2 + y2;
  }
}

// ---------------- GEMM (f32, 64x64 tile) + fused epilogues ----------------
// A(row=(b*N+n), k=(m*CC+c)) = xs[m][n*FDIM + b*CC + c];  B = Wp[k*NCOL+o]
// MODE 0 (gates, NCOL=256): s=sigmoid(g); o<128 -> rh=s*hx ; o>=128 -> u=s
// MODE 1 (cand,  NCOL=128): c=tanh(g); nh = u*hx + (1-u)*c -> out0

template<int NCOL, int MODE>
__global__ __launch_bounds__(256) void k_gemm(
    const float* __restrict__ xs, const float* __restrict__ Wp,
    const float* __restrict__ bias, const float* __restrict__ hx,
    const float* __restrict__ uin, float* __restrict__ out0,
    float* __restrict__ out1, int N, int BN) {
  __shared__ float As[16][68];
  __shared__ float Bs[16][68];
  int tid = threadIdx.x;
  int tx = tid & 15, ty = tid >> 4;
  int R0 = blockIdx.x * 64;
  int O0 = blockIdx.y * 64;
  float acc[4][4] = {};
  for (int kt = 0; kt < KTOT; kt += 16) {
    // A tile: 64 rows x 16 k. thread loads rows R0+ty+16i at kg=kt+tx
    int kg = kt + tx;
    bool kok = kg < KTOT;
    int m = kg / CC, c = kg - m*CC;
    #pragma unroll
    for (int i = 0; i < 4; ++i) {
      int row = R0 + ty + 16*i;
      float v = 0.f;
      if (kok && row < BN) {
        int n = row % N, b = row / N;
        v = xs[((size_t)m*N + n)*FDIM + b*CC + c];
      }
      As[tx][ty + 16*i] = v;
    }
    // B tile: 16 k x 64 cols
    #pragma unroll
    for (int i = 0; i < 4; ++i) {
      int kk = (tid >> 6) + 4*i;
      int cc2 = tid & 63;
      int kgb = kt + kk;
      float v = 0.f;
      if (kgb < KTOT) v = Wp[(size_t)kgb*NCOL + O0 + cc2];
      Bs[kk][cc2] = v;
    }
    __syncthreads();
    #pragma unroll
    for (int kk = 0; kk < 16; ++kk) {
      float4 a4 = *(const float4*)&As[kk][ty*4];
      float4 b4 = *(const float4*)&Bs[kk][tx*4];
      float a[4] = {a4.x, a4.y, a4.z, a4.w};
      float b[4] = {b4.x, b4.y, b4.z, b4.w};
      #pragma unroll
      for (int i = 0; i < 4; ++i)
        #pragma unroll
        for (int j = 0; j < 4; ++j)
          acc[i][j] += a[i]*b[j];
    }
    __syncthreads();
  }
  #pragma unroll
  for (int i = 0; i < 4; ++i) {
    int row = R0 + ty*4 + i;
    if (row >= BN) continue;
    #pragma unroll
    for (int j = 0; j < 4; ++j) {
      int o = O0 + tx*4 + j;
      float g = acc[i][j] + bias[o];
      if (MODE == 0) {
        float s = 1.f/(1.f + expf(-g));
        if (o < RUNITS)
          out0[(size_t)row*RUNITS + o] = s * hx[(size_t)row*RUNITS + o];
        else
          out1[(size_t)row*RUNITS + (o - RUNITS)] = s;
      } else {
        float cv = tanhf(g);
        float uu = uin[(size_t)row*RUNITS + o];
        float h  = hx[(size_t)row*RUNITS + o];
        out0[(size_t)row*RUNITS + o] = uu*h + (1.f - uu)*cv;
      }
    }
  }
}

// ---------------- projection: out[row] = dot(nh[row], w) + b ----------------

__global__ void k_proj(const float* __restrict__ nh, const float* __restrict__ w,
                       const float* __restrict__ bp, float* __restrict__ out, int rows) {
  int gwid = (int)((blockIdx.x*(size_t)blockDim.x + threadIdx.x) >> 6);
  int lane = threadIdx.x & 63;
  if (gwid >= rows) return;
  const float* r = nh + (size_t)gwid*RUNITS;
  float s = r[lane]*w[lane] + r[lane+64]*w[lane+64];
  #pragma unroll
  for (int off = 32; off > 0; off >>= 1) s += __shfl_down(s, off);
  if (lane == 0) out[gwid] = s + bp[0];
}

// ---------------- launcher ----------------

extern "C" void kernel_launch(void* const* d_in, const int* in_sizes, int n_in,
                              void* d_out, int out_size, void* d_ws, size_t ws_size,
                              hipStream_t stream) {
  const float* inputs = (const float*)d_in[0];
  const float* hidden = (const float*)d_in[1];
  const int*   esrc   = (const int*)d_in[2];
  const int*   edst   = (const int*)d_in[3];
  const float* ew     = (const float*)d_in[4];
  const float* Wg     = (const float*)d_in[5];
  const float* bg     = (const float*)d_in[6];
  const float* Wc     = (const float*)d_in[7];
  const float* bc     = (const float*)d_in[8];
  const float* Wpj    = (const float*)d_in[9];
  const float* bpj    = (const float*)d_in[10];

  const int N  = in_sizes[0] / BATCH;
  const int E  = in_sizes[2];
  const int BN = BATCH * N;

  char* p = (char*)d_ws;
  auto alloc = [&](size_t bytes) -> void* {
    void* r = (void*)p;
    p += (bytes + 255) & ~(size_t)255;
    return r;
  };

  float* deg_out = (float*)alloc((size_t)4*N*sizeof(float)); // + deg_in + cnt_f + cnt_b
  float* deg_in  = deg_out + N;
  int*   cnt_f   = (int*)(deg_out + 2*(size_t)N);
  int*   cnt_b   = cnt_f + N;
  int*   ptr_f   = (int*)alloc((size_t)(N+1)*sizeof(int));
  int*   ptr_b   = (int*)alloc((size_t)(N+1)*sizeof(int));
  int*   cur_f   = (int*)alloc((size_t)N*sizeof(int));
  int*   cur_b   = (int*)alloc((size_t)N*sizeof(int));
  int*   col_f   = (int*)alloc((size_t)E*sizeof(int));
  int*   col_b   = (int*)alloc((size_t)E*sizeof(int));
  float* val_f   = (float*)alloc((size_t)E*sizeof(float));
  float* val_b   = (float*)alloc((size_t)E*sizeof(float));
  float* WpG     = (float*)alloc((size_t)KTOT*2*RUNITS*sizeof(float));
  float* WpC     = (float*)alloc((size_t)KTOT*RUNITS*sizeof(float));
  float* xs      = (float*)alloc((size_t)MM*N*FDIM*sizeof(float));
  float* rh      = (float*)alloc((size_t)BN*RUNITS*sizeof(float));
  float* ub      = (float*)alloc((size_t)BN*RUNITS*sizeof(float));

  float* out_y = (float*)d_out;
  float* out_h = out_y + BN;

  float* x0 = xs;
  float* x1 = xs + (size_t)1*N*FDIM;
  float* x2 = xs + (size_t)2*N*FDIM;
  float* x3 = xs + (size_t)3*N*FDIM;
  float* x4 = xs + (size_t)4*N*FDIM;

  const int TB = 256;
  // 1. zero degree/count region
  int zc = 4*N;
  k_zero_i<<<(zc+TB-1)/TB, TB, 0, stream>>>((int*)deg_out, zc);
  // 2. degrees + counts
  k_deg_cnt<<<(E+TB-1)/TB, TB, 0, stream>>>(esrc, edst, ew, E, deg_out, deg_in, cnt_f, cnt_b);
  // 3. scan -> row ptrs
  k_scan2<<<2, 1024, 0, stream>>>(cnt_f, ptr_f, cur_f, cnt_b, ptr_b, cur_b, N);
  // 4. CSR fill with normalized weights
  k_fill<<<(E+TB-1)/TB, TB, 0, stream>>>(esrc, edst, ew, E, deg_out, deg_in,
                                         cur_f, cur_b, col_f, val_f, col_b, val_b);
  // 5. pack weights
  {
    int tg = KTOT*2*RUNITS, tc = KTOT*RUNITS;
    k_pack<<<(tg+TB-1)/TB, TB, 0, stream>>>(Wg, WpG, 2*RUNITS);
    k_pack<<<(tc+TB-1)/TB, TB, 0, stream>>>(Wc, WpC, RUNITS);
  }
  size_t xtot = (size_t)N*FDIM;
  int xblocks = (int)((xtot + TB - 1)/TB);

  // ---- gates gconv ----
  k_build_x0<<<xblocks, TB, 0, stream>>>(inputs, hidden, x0, N);
  k_spmm<<<N, TB, 0, stream>>>(ptr_f, col_f, val_f, x0, x0, x1, 1.f, 0.f);
  k_spmm<<<N, TB, 0, stream>>>(ptr_f, col_f, val_f, x1, x0, x2, 2.f, -1.f);
  k_spmm<<<N, TB, 0, stream>>>(ptr_b, col_b, val_b, x0, x0, x3, 1.f, 0.f);
  k_spmm<<<N, TB, 0, stream>>>(ptr_b, col_b, val_b, x3, x0, x4, 2.f, -1.f);
  k_gemm<2*RUNITS, 0><<<dim3((BN+63)/64, (2*RUNITS)/64), TB, 0, stream>>>(
      xs, WpG, bg, hidden, nullptr, rh, ub, N, BN);

  // ---- candidate gconv (hx replaced by r*hx) ----
  k_build_x0<<<xblocks, TB, 0, stream>>>(inputs, rh, x0, N);
  k_spmm<<<N, TB, 0, stream>>>(ptr_f, col_f, val_f, x0, x0, x1, 1.f, 0.f);
  k_spmm<<<N, TB, 0, stream>>>(ptr_f, col_f, val_f, x1, x0, x2, 2.f, -1.f);
  k_spmm<<<N, TB, 0, stream>>>(ptr_b, col_b, val_b, x0, x0, x3, 1.f, 0.f);
  k_spmm<<<N, TB, 0, stream>>>(ptr_b, col_b, val_b, x3, x0, x4, 2.f, -1.f);
  k_gemm<RUNITS, 1><<<dim3((BN+63)/64, RUNITS/64), TB, 0, stream>>>(
      xs, WpC, bc, hidden, ub, out_h, nullptr, N, BN);

  // ---- projection ----
  k_proj<<<(BN*64 + TB - 1)/TB, TB, 0, stream>>>(out_h, Wpj, bpj, out_y, BN);
}

// Round 2
// 569.175 us; speedup vs baseline: 1.6615x; 1.6615x over previous
//
#include <hip/hip_runtime.h>
#include <cstdint>
#include <cstddef>

#define BATCH  4
#define RUNITS 128
#define CC     129            // 1 + RUNITS
#define MM     5              // 2*K+1
#define FDIM   516            // BATCH*CC
#define PAIRS  258            // FDIM/2
#define CP     136            // per-m padded channel count (mult of 8)
#define KP     704            // padded K' (22*32); real = MM*CP = 680

typedef unsigned int  uint32;
typedef unsigned short ushort16;
typedef __attribute__((ext_vector_type(8))) short short8;
typedef __attribute__((ext_vector_type(4))) float f32x4;

__device__ inline float bflo(uint32 u){ return __uint_as_float(u << 16); }
__device__ inline float bfhi(uint32 u){ return __uint_as_float(u & 0xFFFF0000u); }
__device__ inline ushort16 f2bf(float f){
  uint32 u = __float_as_uint(f);
  return (ushort16)((u + 0x7FFFu + ((u >> 16) & 1u)) >> 16);
}
__device__ inline uint32 packbf(float a, float b){
  return (uint32)f2bf(a) | ((uint32)f2bf(b) << 16);
}

// ---------------- graph prep ----------------

__global__ void k_zero_i(int* p, int n) {
  int i = blockIdx.x*blockDim.x + threadIdx.x;
  if (i < n) p[i] = 0;
}

__global__ void k_deg_cnt(const int* __restrict__ src, const int* __restrict__ dst,
                          const float* __restrict__ w, int E,
                          float* deg_out, float* deg_in, int* cnt_f, int* cnt_b) {
  int e = blockIdx.x*blockDim.x + threadIdx.x;
  if (e >= E) return;
  int s = src[e], d = dst[e]; float we = w[e];
  atomicAdd(&deg_out[s], we);
  atomicAdd(&deg_in[d], we);
  atomicAdd(&cnt_f[s], 1);
  atomicAdd(&cnt_b[d], 1);
}

__global__ __launch_bounds__(1024) void k_scan2(
    const int* __restrict__ cnt_f, int* ptr_f, int* cur_f,
    const int* __restrict__ cnt_b, int* ptr_b, int* cur_b, int n) {
  const int* cnt = (blockIdx.x == 0) ? cnt_f : cnt_b;
  int* ptr = (blockIdx.x == 0) ? ptr_f : ptr_b;
  int* cur = (blockIdx.x == 0) ? cur_f : cur_b;
  __shared__ int sm[1024];
  __shared__ int carry_s;
  int tid = threadIdx.x;
  if (tid == 0) carry_s = 0;
  __syncthreads();
  for (int base = 0; base < n; base += 1024) {
    int i = base + tid;
    int v = (i < n) ? cnt[i] : 0;
    sm[tid] = v;
    __syncthreads();
    int acc = v;
    for (int off = 1; off < 1024; off <<= 1) {
      int t = (tid >= off) ? sm[tid - off] : 0;
      __syncthreads();
      acc += t;
      sm[tid] = acc;
      __syncthreads();
    }
    int carry = carry_s;
    if (i < n) { ptr[i] = carry + acc - v; cur[i] = carry + acc - v; }
    __syncthreads();
    if (tid == 1023) carry_s = carry + sm[1023];
    __syncthreads();
  }
  if (tid == 0) ptr[n] = carry_s;
}

__global__ void k_fill(const int* __restrict__ src, const int* __restrict__ dst,
                       const float* __restrict__ w, int E,
                       const float* __restrict__ deg_out, const float* __restrict__ deg_in,
                       int* cur_f, int* cur_b,
                       int* col_f, float* val_f, int* col_b, float* val_b) {
  int e = blockIdx.x*blockDim.x + threadIdx.x;
  if (e >= E) return;
  int s = src[e], d = dst[e]; float we = w[e];
  int pf = atomicAdd(&cur_f[s], 1);
  col_f[pf] = d; val_f[pf] = we / deg_out[s];
  int pb = atomicAdd(&cur_b[d], 1);
  col_b[pb] = s; val_b[pb] = we / deg_in[d];
}

// ---------------- weight pack: Wt[o][k'=m*CP+c] (bf16, zero pads) ----------------

__global__ void k_packw(const float* __restrict__ W, ushort16* __restrict__ Wt, int ncol) {
  int idx = blockIdx.x*blockDim.x + threadIdx.x;
  int total = ncol * KP;
  if (idx >= total) return;
  int o = idx / KP, k = idx - o*KP;
  int m = k / CP, c = k - m*CP;
  float v = (m < MM && c < CC) ? W[(size_t)(c*MM + m)*ncol + o] : 0.f;
  Wt[idx] = f2bf(v);
}

// ---------------- feature assembly ----------------
// xw:  (N, PAIRS) packed bf16 pairs, f = b*CC + c
// xsbf: (BATCH*N, KP) bf16, k' = m*CP + c  (pads = garbage, killed by Wt zeros)

template<bool HBF>
__global__ __launch_bounds__(256) void k_build_x0(
    const float* __restrict__ inp, const void* __restrict__ hsrc,
    uint32* __restrict__ xw, ushort16* __restrict__ xsbf, int N) {
  int n = blockIdx.x, t = threadIdx.x;
  const float* hf = (const float*)hsrc;
  const ushort16* hb = (const ushort16*)hsrc;
  for (int p = t; p < PAIRS; p += 256) {
    float v[2];
    #pragma unroll
    for (int s = 0; s < 2; ++s) {
      int f = 2*p + s;
      int b = f / CC, c = f - b*CC;
      size_t r = (size_t)b*N + n;
      float x;
      if (c == 0) x = inp[r];
      else {
        size_t hi = r*RUNITS + (c-1);
        x = HBF ? __uint_as_float(((uint32)hb[hi]) << 16) : hf[hi];
      }
      v[s] = x;
      xsbf[r*KP + c] = f2bf(x);
    }
    xw[(size_t)n*PAIRS + p] = packbf(v[0], v[1]);
  }
}

// ---------------- SPMM: acc = sum val*X[col]; out = alpha*acc + beta*Y ----------------

template<bool WW, bool HY>
__global__ __launch_bounds__(256) void k_spmm(
    const int* __restrict__ ptr, const int* __restrict__ col, const float* __restrict__ val,
    const uint32* __restrict__ X, const uint32* __restrict__ Y,
    uint32* __restrict__ Xout, ushort16* __restrict__ xsbf,
    int N, int level, float alpha, float beta) {
  int n = blockIdx.x, t = threadIdx.x;
  int s = ptr[n], e = ptr[n+1];
  float a00=0.f, a01=0.f, a10=0.f, a11=0.f;
  for (int i = s; i < e; ++i) {
    int c = col[i]; float v = val[i];
    const uint32* Xr = X + (size_t)c*PAIRS;
    uint32 u0 = Xr[t];
    a00 += v*bflo(u0); a01 += v*bfhi(u0);
    if (t < 2) { uint32 u1 = Xr[256+t]; a10 += v*bflo(u1); a11 += v*bfhi(u1); }
  }
  size_t base = (size_t)n*PAIRS;
  int loff = level*CP;
  {
    float r0 = alpha*a00, r1 = alpha*a01;
    if (HY) { uint32 y = Y[base+t]; r0 += beta*bflo(y); r1 += beta*bfhi(y); }
    if (WW) Xout[base+t] = packbf(r0, r1);
    int f = 2*t;   int b0 = f/CC,  c0 = f - b0*CC;
    xsbf[((size_t)b0*N + n)*KP + loff + c0] = f2bf(r0);
    int f1 = f+1;  int b1 = f1/CC, c1 = f1 - b1*CC;
    xsbf[((size_t)b1*N + n)*KP + loff + c1] = f2bf(r1);
  }
  if (t < 2) {
    float r0 = alpha*a10, r1 = alpha*a11;
    if (HY) { uint32 y = Y[base+256+t]; r0 += beta*bflo(y); r1 += beta*bfhi(y); }
    if (WW) Xout[base+256+t] = packbf(r0, r1);
    int f = 2*(256+t); int b0 = f/CC,  c0 = f - b0*CC;
    xsbf[((size_t)b0*N + n)*KP + loff + c0] = f2bf(r0);
    int f1 = f+1;      int b1 = f1/CC, c1 = f1 - b1*CC;
    xsbf[((size_t)b1*N + n)*KP + loff + c1] = f2bf(r1);
  }
}

// ---------------- MFMA GEMM: C[row][o] = A[row][:] @ Wt[o][:] + bias ----------------
// 128x128 tile, 4 waves (2x2), wave tile 64x64, BK=32, mfma_f32_16x16x32_bf16
// MODE 0 (gates): s=sigmoid(g); o<128 -> rh(bf16)=s*hx ; o>=128 -> u(f32)=s
// MODE 1 (cand):  c=tanh(g);  out_h(f32) = u*hx + (1-u)*c

template<int NCOL, int MODE>
__global__ __launch_bounds__(256) void k_gemm(
    const ushort16* __restrict__ A, const ushort16* __restrict__ Bt,
    const float* __restrict__ bias, const float* __restrict__ hx,
    const float* __restrict__ uin, void* __restrict__ out0,
    float* __restrict__ out1, int BN) {
  __shared__ __align__(16) ushort16 Al[128][40];   // stride 80B: 2-way banks (free)
  __shared__ __align__(16) ushort16 Bl[128][40];
  int tid = threadIdx.x;
  int lane = tid & 63, wave = tid >> 6;
  int wm = wave >> 1, wn = wave & 1;
  int R0 = blockIdx.x * 128, O0 = blockIdx.y * 128;

  f32x4 acc[4][4];
  #pragma unroll
  for (int i = 0; i < 4; ++i)
    #pragma unroll
    for (int j = 0; j < 4; ++j)
      acc[i][j] = (f32x4){0.f, 0.f, 0.f, 0.f};

  int sr = tid >> 1;            // 0..127: A row / Bt col
  int sh = (tid & 1) * 16;      // k-sub-chunk
  int arow = R0 + sr; if (arow >= BN) arow = BN - 1;
  const ushort16* Ap = A  + (size_t)arow*KP + sh;
  const ushort16* Bp = Bt + (size_t)(O0 + sr)*KP + sh;

  uint4 ra0 = *(const uint4*)Ap,     ra1 = *(const uint4*)(Ap + 8);
  uint4 rb0 = *(const uint4*)Bp,     rb1 = *(const uint4*)(Bp + 8);

  int fr = lane & 15, g8 = (lane >> 4) * 8;

  for (int kt = 0; kt < KP; kt += 32) {
    __syncthreads();
    *(uint4*)&Al[sr][sh]   = ra0;  *(uint4*)&Al[sr][sh+8] = ra1;
    *(uint4*)&Bl[sr][sh]   = rb0;  *(uint4*)&Bl[sr][sh+8] = rb1;
    __syncthreads();
    if (kt + 32 < KP) {
      ra0 = *(const uint4*)(Ap + kt + 32); ra1 = *(const uint4*)(Ap + kt + 40);
      rb0 = *(const uint4*)(Bp + kt + 32); rb1 = *(const uint4*)(Bp + kt + 40);
    }
    short8 af[4], bv[4];
    #pragma unroll
    for (int i = 0; i < 4; ++i) af[i] = *(const short8*)&Al[wm*64 + i*16 + fr][g8];
    #pragma unroll
    for (int j = 0; j < 4; ++j) bv[j] = *(const short8*)&Bl[wn*64 + j*16 + fr][g8];
    #pragma unroll
    for (int i = 0; i < 4; ++i)
      #pragma unroll
      for (int j = 0; j < 4; ++j)
        acc[i][j] = __builtin_amdgcn_mfma_f32_16x16x32_bf16(af[i], bv[j], acc[i][j], 0, 0, 0);
  }

  int cl = lane & 15, rq = (lane >> 4) * 4;
  #pragma unroll
  for (int i = 0; i < 4; ++i) {
    #pragma unroll
    for (int q = 0; q < 4; ++q) {
      int row = R0 + wm*64 + i*16 + rq + q;
      if (row >= BN) continue;
      #pragma unroll
      for (int j = 0; j < 4; ++j) {
        int o = O0 + wn*64 + j*16 + cl;
        float g = acc[i][j][q] + bias[o];
        if (MODE == 0) {
          float sg = 1.f / (1.f + expf(-g));
          if (o < RUNITS)
            ((ushort16*)out0)[(size_t)row*RUNITS + o] = f2bf(sg * hx[(size_t)row*RUNITS + o]);
          else
            out1[(size_t)row*RUNITS + (o - RUNITS)] = sg;
        } else {
          float cv = tanhf(g);
          float uu = uin[(size_t)row*RUNITS + o];
          float hh = hx[(size_t)row*RUNITS + o];
          ((float*)out0)[(size_t)row*RUNITS + o] = uu*hh + (1.f - uu)*cv;
        }
      }
    }
  }
}

// ---------------- projection ----------------

__global__ void k_proj(const float* __restrict__ nh, const float* __restrict__ w,
                       const float* __restrict__ bp, float* __restrict__ out, int rows) {
  int gwid = (int)((blockIdx.x*(size_t)blockDim.x + threadIdx.x) >> 6);
  int lane = threadIdx.x & 63;
  if (gwid >= rows) return;
  const float* r = nh + (size_t)gwid*RUNITS;
  float s = r[lane]*w[lane] + r[lane+64]*w[lane+64];
  #pragma unroll
  for (int off = 32; off > 0; off >>= 1) s += __shfl_down(s, off);
  if (lane == 0) out[gwid] = s + bp[0];
}

// ---------------- launcher ----------------

extern "C" void kernel_launch(void* const* d_in, const int* in_sizes, int n_in,
                              void* d_out, int out_size, void* d_ws, size_t ws_size,
                              hipStream_t stream) {
  const float* inputs = (const float*)d_in[0];
  const float* hidden = (const float*)d_in[1];
  const int*   esrc   = (const int*)d_in[2];
  const int*   edst   = (const int*)d_in[3];
  const float* ew     = (const float*)d_in[4];
  const float* Wg     = (const float*)d_in[5];
  const float* bg     = (const float*)d_in[6];
  const float* Wc     = (const float*)d_in[7];
  const float* bc     = (const float*)d_in[8];
  const float* Wpj    = (const float*)d_in[9];
  const float* bpj    = (const float*)d_in[10];

  const int N  = in_sizes[0] / BATCH;
  const int E  = in_sizes[2];
  const int BN = BATCH * N;

  char* p = (char*)d_ws;
  auto alloc = [&](size_t bytes) -> void* {
    void* r = (void*)p;
    p += (bytes + 255) & ~(size_t)255;
    return r;
  };

  float* deg_out = (float*)alloc((size_t)4*N*sizeof(float));
  float* deg_in  = deg_out + N;
  int*   cnt_f   = (int*)(deg_out + 2*(size_t)N);
  int*   cnt_b   = cnt_f + N;
  int*   ptr_f   = (int*)alloc((size_t)(N+1)*sizeof(int));
  int*   ptr_b   = (int*)alloc((size_t)(N+1)*sizeof(int));
  int*   cur_f   = (int*)alloc((size_t)N*sizeof(int));
  int*   cur_b   = (int*)alloc((size_t)N*sizeof(int));
  int*   col_f   = (int*)alloc((size_t)E*sizeof(int));
  int*   col_b   = (int*)alloc((size_t)E*sizeof(int));
  float* val_f   = (float*)alloc((size_t)E*sizeof(float));
  float* val_b   = (float*)alloc((size_t)E*sizeof(float));
  ushort16* WtG  = (ushort16*)alloc((size_t)2*RUNITS*KP*sizeof(ushort16));
  ushort16* WtC  = (ushort16*)alloc((size_t)RUNITS*KP*sizeof(ushort16));
  ushort16* xsbf = (ushort16*)alloc((size_t)BN*KP*sizeof(ushort16));
  uint32* x0w    = (uint32*)alloc((size_t)N*PAIRS*sizeof(uint32));
  uint32* x1w    = (uint32*)alloc((size_t)N*PAIRS*sizeof(uint32));
  ushort16* rh   = (ushort16*)alloc((size_t)BN*RUNITS*sizeof(ushort16));
  float* ub      = (float*)alloc((size_t)BN*RUNITS*sizeof(float));

  float* out_y = (float*)d_out;
  float* out_h = out_y + BN;

  const int TB = 256;
  int zc = 4*N;
  k_zero_i<<<(zc+TB-1)/TB, TB, 0, stream>>>((int*)deg_out, zc);
  k_deg_cnt<<<(E+TB-1)/TB, TB, 0, stream>>>(esrc, edst, ew, E, deg_out, deg_in, cnt_f, cnt_b);
  k_scan2<<<2, 1024, 0, stream>>>(cnt_f, ptr_f, cur_f, cnt_b, ptr_b, cur_b, N);
  k_fill<<<(E+TB-1)/TB, TB, 0, stream>>>(esrc, edst, ew, E, deg_out, deg_in,
                                         cur_f, cur_b, col_f, val_f, col_b, val_b);
  {
    int tg = 2*RUNITS*KP, tc = RUNITS*KP;
    k_packw<<<(tg+TB-1)/TB, TB, 0, stream>>>(Wg, WtG, 2*RUNITS);
    k_packw<<<(tc+TB-1)/TB, TB, 0, stream>>>(Wc, WtC, RUNITS);
  }

  int gx = (BN + 127) / 128;

  // ---- gates gconv ----
  k_build_x0<false><<<N, TB, 0, stream>>>(inputs, hidden, x0w, xsbf, N);
  k_spmm<true ,false><<<N, TB, 0, stream>>>(ptr_f, col_f, val_f, x0w, x0w, x1w, xsbf, N, 1, 1.f,  0.f);
  k_spmm<false,true ><<<N, TB, 0, stream>>>(ptr_f, col_f, val_f, x1w, x0w, x1w, xsbf, N, 2, 2.f, -1.f);
  k_spmm<true ,false><<<N, TB, 0, stream>>>(ptr_b, col_b, val_b, x0w, x0w, x1w, xsbf, N, 3, 1.f,  0.f);
  k_spmm<false,true ><<<N, TB, 0, stream>>>(ptr_b, col_b, val_b, x1w, x0w, x1w, xsbf, N, 4, 2.f, -1.f);
  k_gemm<2*RUNITS, 0><<<dim3(gx, 2), TB, 0, stream>>>(
      xsbf, WtG, bg, hidden, nullptr, rh, ub, BN);

  // ---- candidate gconv (hx replaced by r*hx, bf16) ----
  k_build_x0<true><<<N, TB, 0, stream>>>(inputs, rh, x0w, xsbf, N);
  k_spmm<true ,false><<<N, TB, 0, stream>>>(ptr_f, col_f, val_f, x0w, x0w, x1w, xsbf, N, 1, 1.f,  0.f);
  k_spmm<false,true ><<<N, TB, 0, stream>>>(ptr_f, col_f, val_f, x1w, x0w, x1w, xsbf, N, 2, 2.f, -1.f);
  k_spmm<true ,false><<<N, TB, 0, stream>>>(ptr_b, col_b, val_b, x0w, x0w, x1w, xsbf, N, 3, 1.f,  0.f);
  k_spmm<false,true ><<<N, TB, 0, stream>>>(ptr_b, col_b, val_b, x1w, x0w, x1w, xsbf, N, 4, 2.f, -1.f);
  k_gemm<RUNITS, 1><<<dim3(gx, 1), TB, 0, stream>>>(
      xsbf, WtC, bc, hidden, ub, out_h, nullptr, BN);

  // ---- projection ----
  k_proj<<<((size_t)BN*64 + TB - 1)/TB, TB, 0, stream>>>(out_h, Wpj, bpj, out_y, BN);
}

// Round 3
// 547.534 us; speedup vs baseline: 1.7272x; 1.0395x over previous
//
#include <hip/hip_runtime.h>
#include <cstdint>
#include <cstddef>

#define BATCH  4
#define RUNITS 128
#define CC     129            // 1 + RUNITS
#define MM     5              // 2*K+1
#define FDIM   516            // BATCH*CC
#define PAIRS  258            // FDIM/2 (uint32 words of 2 bf16)
#define PW     260            // padded row stride in words (1040 B, 16B-aligned)
#define CP     136            // per-m padded channel count
#define KP     704            // padded K' (22*32); real = MM*CP = 680

typedef unsigned int  uint32;
typedef unsigned short ushort16;
typedef __attribute__((ext_vector_type(8))) short short8;
typedef __attribute__((ext_vector_type(4))) float f32x4;

__device__ inline float bflo(uint32 u){ return __uint_as_float(u << 16); }
__device__ inline float bfhi(uint32 u){ return __uint_as_float(u & 0xFFFF0000u); }
__device__ inline ushort16 f2bf(float f){
  uint32 u = __float_as_uint(f);
  return (ushort16)((u + 0x7FFFu + ((u >> 16) & 1u)) >> 16);
}
__device__ inline uint32 packbf(float a, float b){
  return (uint32)f2bf(a) | ((uint32)f2bf(b) << 16);
}
__device__ inline float bf2f(ushort16 v){ return __uint_as_float(((uint32)v) << 16); }

// ---------------- graph prep ----------------

__global__ void k_zero_i(int* p, int n) {
  int i = blockIdx.x*blockDim.x + threadIdx.x;
  if (i < n) p[i] = 0;
}

__global__ void k_deg_cnt(const int* __restrict__ src, const int* __restrict__ dst,
                          const float* __restrict__ w, int E,
                          float* deg_out, float* deg_in, int* cnt_f, int* cnt_b) {
  int e = blockIdx.x*blockDim.x + threadIdx.x;
  if (e >= E) return;
  int s = src[e], d = dst[e]; float we = w[e];
  atomicAdd(&deg_out[s], we);
  atomicAdd(&deg_in[d], we);
  atomicAdd(&cnt_f[s], 1);
  atomicAdd(&cnt_b[d], 1);
}

__global__ __launch_bounds__(1024) void k_scan2(
    const int* __restrict__ cnt_f, int* ptr_f, int* cur_f,
    const int* __restrict__ cnt_b, int* ptr_b, int* cur_b, int n) {
  const int* cnt = (blockIdx.x == 0) ? cnt_f : cnt_b;
  int* ptr = (blockIdx.x == 0) ? ptr_f : ptr_b;
  int* cur = (blockIdx.x == 0) ? cur_f : cur_b;
  __shared__ int sm[1024];
  __shared__ int carry_s;
  int tid = threadIdx.x;
  if (tid == 0) carry_s = 0;
  __syncthreads();
  for (int base = 0; base < n; base += 1024) {
    int i = base + tid;
    int v = (i < n) ? cnt[i] : 0;
    sm[tid] = v;
    __syncthreads();
    int acc = v;
    for (int off = 1; off < 1024; off <<= 1) {
      int t = (tid >= off) ? sm[tid - off] : 0;
      __syncthreads();
      acc += t;
      sm[tid] = acc;
      __syncthreads();
    }
    int carry = carry_s;
    if (i < n) { ptr[i] = carry + acc - v; cur[i] = carry + acc - v; }
    __syncthreads();
    if (tid == 1023) carry_s = carry + sm[1023];
    __syncthreads();
  }
  if (tid == 0) ptr[n] = carry_s;
}

__global__ void k_fill(const int* __restrict__ src, const int* __restrict__ dst,
                       const float* __restrict__ w, int E,
                       const float* __restrict__ deg_out, const float* __restrict__ deg_in,
                       int* cur_f, int* cur_b,
                       int* col_f, float* val_f, int* col_b, float* val_b) {
  int e = blockIdx.x*blockDim.x + threadIdx.x;
  if (e >= E) return;
  int s = src[e], d = dst[e]; float we = w[e];
  int pf = atomicAdd(&cur_f[s], 1);
  col_f[pf] = d; val_f[pf] = we / deg_out[s];
  int pb = atomicAdd(&cur_b[d], 1);
  col_b[pb] = s; val_b[pb] = we / deg_in[d];
}

// ---------------- weight pack: Wt[o][k'=m*CP+c] (bf16, zero pads) ----------------

__global__ void k_packw(const float* __restrict__ W, ushort16* __restrict__ Wt, int ncol) {
  int idx = blockIdx.x*blockDim.x + threadIdx.x;
  int total = ncol * KP;
  if (idx >= total) return;
  int o = idx / KP, k = idx - o*KP;
  int m = k / CP, c = k - m*CP;
  float v = (m < MM && c < CC) ? W[(size_t)(c*MM + m)*ncol + o] : 0.f;
  Wt[idx] = f2bf(v);
}

// ---------------- feature assembly ----------------
// xw:  (N, PW) packed bf16 pairs (words 0..257 valid), f = b*CC + c
// xsbf: (BATCH*N, KP) bf16, k' = m*CP + c  (pads garbage, killed by Wt zeros)

template<bool HBF>
__global__ __launch_bounds__(256) void k_build_x0(
    const float* __restrict__ inp, const void* __restrict__ hsrc,
    uint32* __restrict__ xw, ushort16* __restrict__ xsbf, int N) {
  int n = blockIdx.x, t = threadIdx.x;
  const float* hf = (const float*)hsrc;
  const ushort16* hb = (const ushort16*)hsrc;
  for (int p = t; p < PAIRS; p += 256) {
    float v[2];
    #pragma unroll
    for (int s = 0; s < 2; ++s) {
      int f = 2*p + s;
      int b = f / CC, c = f - b*CC;
      size_t r = (size_t)b*N + n;
      float x;
      if (c == 0) x = inp[r];
      else {
        size_t hi = r*RUNITS + (c-1);
        x = HBF ? bf2f(hb[hi]) : hf[hi];
      }
      v[s] = x;
      xsbf[r*KP + c] = f2bf(x);
    }
    xw[(size_t)n*PW + p] = packbf(v[0], v[1]);
  }
}

// ---------------- SPMM: wave-per-row; out = alpha*sum(val*X[col]) + beta*Y ----------------

template<bool WW, bool HY>
__global__ __launch_bounds__(256) void k_spmm(
    const int* __restrict__ ptr, const int* __restrict__ col, const float* __restrict__ val,
    const uint32* __restrict__ X, const uint32* __restrict__ Y,
    uint32* __restrict__ Xout, ushort16* __restrict__ xsbf,
    int N, int level, float alpha, float beta) {
  int wv = threadIdx.x >> 6, lane = threadIdx.x & 63;
  int n = blockIdx.x*4 + wv;
  if (n >= N) return;
  int s = ptr[n], e = ptr[n+1];
  const int wl = 4*lane;
  float a[8] = {0.f,0.f,0.f,0.f,0.f,0.f,0.f,0.f};
  float t0 = 0.f, t1 = 0.f;
  #pragma unroll 2
  for (int i = s; i < e; ++i) {
    int c = col[i]; float v = val[i];
    const uint32* Xr = X + (size_t)c*PW;
    uint4 u = *(const uint4*)(Xr + wl);
    a[0] += v*bflo(u.x); a[1] += v*bfhi(u.x);
    a[2] += v*bflo(u.y); a[3] += v*bfhi(u.y);
    a[4] += v*bflo(u.z); a[5] += v*bfhi(u.z);
    a[6] += v*bflo(u.w); a[7] += v*bfhi(u.w);
    if (lane < 2) { uint32 uw = Xr[256+lane]; t0 += v*bflo(uw); t1 += v*bfhi(uw); }
  }
  float r[8];
  if (HY) {
    uint4 yv = *(const uint4*)(Y + (size_t)n*PW + wl);
    r[0] = alpha*a[0] + beta*bflo(yv.x); r[1] = alpha*a[1] + beta*bfhi(yv.x);
    r[2] = alpha*a[2] + beta*bflo(yv.y); r[3] = alpha*a[3] + beta*bfhi(yv.y);
    r[4] = alpha*a[4] + beta*bflo(yv.z); r[5] = alpha*a[5] + beta*bfhi(yv.z);
    r[6] = alpha*a[6] + beta*bflo(yv.w); r[7] = alpha*a[7] + beta*bfhi(yv.w);
  } else {
    #pragma unroll
    for (int s2 = 0; s2 < 8; ++s2) r[s2] = alpha*a[s2];
  }
  if (WW) {
    uint4 ov;
    ov.x = packbf(r[0], r[1]); ov.y = packbf(r[2], r[3]);
    ov.z = packbf(r[4], r[5]); ov.w = packbf(r[6], r[7]);
    *(uint4*)(Xout + (size_t)n*PW + wl) = ov;
  }
  // scatter into GEMM A matrix
  int loff = level*CP;
  int f0 = 8*lane;
  int b0 = f0 / CC, c0 = f0 - b0*CC;
  if (c0 <= CC - 8) {      // all 8 features in same batch row: one 16B store
    short8 pk;
    #pragma unroll
    for (int s2 = 0; s2 < 8; ++s2) pk[s2] = (short)f2bf(r[s2]);
    *(short8*)&xsbf[((size_t)b0*N + n)*KP + loff + c0] = pk;
  } else {
    #pragma unroll
    for (int s2 = 0; s2 < 8; ++s2) {
      int f = f0 + s2; int b = f / CC; int c2 = f - b*CC;
      xsbf[((size_t)b*N + n)*KP + loff + c2] = f2bf(r[s2]);
    }
  }
  if (lane < 2) {
    float q0, q1;
    if (HY) {
      uint32 yw = Y[(size_t)n*PW + 256 + lane];
      q0 = alpha*t0 + beta*bflo(yw); q1 = alpha*t1 + beta*bfhi(yw);
    } else { q0 = alpha*t0; q1 = alpha*t1; }
    if (WW) Xout[(size_t)n*PW + 256 + lane] = packbf(q0, q1);
    int f = 512 + 2*lane;            // b=3, c=125..128
    int c2 = f - 3*CC;
    xsbf[((size_t)3*N + n)*KP + loff + c2]     = f2bf(q0);
    xsbf[((size_t)3*N + n)*KP + loff + c2 + 1] = f2bf(q1);
  }
}

// ---------------- barrier-free register GEMM ----------------
// wave-tile WR x 64; A and Bt read straight global -> MFMA frags (no LDS).
// MODE 0 (gates): s=sigmoid(g); o<128 -> rh(bf16)=s*hx ; o>=128 -> u(bf16)=s
// MODE 1 (cand):  c=tanh(g);  out_h(f32) = u*hx + (1-u)*c

template<int WR, int MODE>
__global__ __launch_bounds__(256) void k_gemm(
    const ushort16* __restrict__ A, const ushort16* __restrict__ Bt,
    const float* __restrict__ bias, const float* __restrict__ hx,
    const ushort16* __restrict__ uin, void* __restrict__ out0,
    ushort16* __restrict__ out1, int BN) {
  constexpr int NI = WR/16;
  int lane = threadIdx.x & 63, wv = threadIdx.x >> 6;
  int fr = lane & 15, g = lane >> 4;
  int R0 = (blockIdx.x*4 + wv) * WR;
  int O0 = blockIdx.y * 64;

  const ushort16* Ap[NI];
  #pragma unroll
  for (int i = 0; i < NI; ++i) {
    int row = R0 + i*16 + fr; if (row >= BN) row = BN - 1;
    Ap[i] = A + (size_t)row*KP + g*8;
  }
  const ushort16* Bp[4];
  #pragma unroll
  for (int j = 0; j < 4; ++j)
    Bp[j] = Bt + (size_t)(O0 + j*16 + fr)*KP + g*8;

  f32x4 acc[NI][4];
  #pragma unroll
  for (int i = 0; i < NI; ++i)
    #pragma unroll
    for (int j = 0; j < 4; ++j)
      acc[i][j] = (f32x4){0.f,0.f,0.f,0.f};

  short8 ac[NI], bc[4], an[NI], bn[4];
  #pragma unroll
  for (int i = 0; i < NI; ++i) ac[i] = *(const short8*)(Ap[i]);
  #pragma unroll
  for (int j = 0; j < 4; ++j)  bc[j] = *(const short8*)(Bp[j]);

  #pragma unroll
  for (int kt = 32; kt <= KP; kt += 32) {
    if (kt < KP) {
      #pragma unroll
      for (int i = 0; i < NI; ++i) an[i] = *(const short8*)(Ap[i] + kt);
      #pragma unroll
      for (int j = 0; j < 4; ++j)  bn[j] = *(const short8*)(Bp[j] + kt);
    }
    #pragma unroll
    for (int i = 0; i < NI; ++i)
      #pragma unroll
      for (int j = 0; j < 4; ++j)
        acc[i][j] = __builtin_amdgcn_mfma_f32_16x16x32_bf16(ac[i], bc[j], acc[i][j], 0, 0, 0);
    if (kt < KP) {
      #pragma unroll
      for (int i = 0; i < NI; ++i) ac[i] = an[i];
      #pragma unroll
      for (int j = 0; j < 4; ++j)  bc[j] = bn[j];
    }
  }

  #pragma unroll
  for (int i = 0; i < NI; ++i) {
    #pragma unroll
    for (int q = 0; q < 4; ++q) {
      int row = R0 + i*16 + g*4 + q;
      if (row >= BN) continue;
      #pragma unroll
      for (int j = 0; j < 4; ++j) {
        int o = O0 + j*16 + fr;
        float gv = acc[i][j][q] + bias[o];
        if (MODE == 0) {
          float sg = 1.f/(1.f + expf(-gv));
          if (o < RUNITS)
            ((ushort16*)out0)[(size_t)row*RUNITS + o] = f2bf(sg * hx[(size_t)row*RUNITS + o]);
          else
            out1[(size_t)row*RUNITS + (o - RUNITS)] = f2bf(sg);
        } else {
          float cv = tanhf(gv);
          float uu = bf2f(uin[(size_t)row*RUNITS + o]);
          float hh = hx[(size_t)row*RUNITS + o];
          ((float*)out0)[(size_t)row*RUNITS + o] = uu*hh + (1.f - uu)*cv;
        }
      }
    }
  }
}

// ---------------- projection ----------------

__global__ void k_proj(const float* __restrict__ nh, const float* __restrict__ w,
                       const float* __restrict__ bp, float* __restrict__ out, int rows) {
  int gwid = (int)((blockIdx.x*(size_t)blockDim.x + threadIdx.x) >> 6);
  int lane = threadIdx.x & 63;
  if (gwid >= rows) return;
  const float* r = nh + (size_t)gwid*RUNITS;
  float s = r[lane]*w[lane] + r[lane+64]*w[lane+64];
  #pragma unroll
  for (int off = 32; off > 0; off >>= 1) s += __shfl_down(s, off);
  if (lane == 0) out[gwid] = s + bp[0];
}

// ---------------- launcher ----------------

extern "C" void kernel_launch(void* const* d_in, const int* in_sizes, int n_in,
                              void* d_out, int out_size, void* d_ws, size_t ws_size,
                              hipStream_t stream) {
  const float* inputs = (const float*)d_in[0];
  const float* hidden = (const float*)d_in[1];
  const int*   esrc   = (const int*)d_in[2];
  const int*   edst   = (const int*)d_in[3];
  const float* ew     = (const float*)d_in[4];
  const float* Wg     = (const float*)d_in[5];
  const float* bg     = (const float*)d_in[6];
  const float* Wc     = (const float*)d_in[7];
  const float* bc     = (const float*)d_in[8];
  const float* Wpj    = (const float*)d_in[9];
  const float* bpj    = (const float*)d_in[10];

  const int N  = in_sizes[0] / BATCH;
  const int E  = in_sizes[2];
  const int BN = BATCH * N;

  char* p = (char*)d_ws;
  auto alloc = [&](size_t bytes) -> void* {
    void* r = (void*)p;
    p += (bytes + 255) & ~(size_t)255;
    return r;
  };

  float* deg_out = (float*)alloc((size_t)4*N*sizeof(float));
  float* deg_in  = deg_out + N;
  int*   cnt_f   = (int*)(deg_out + 2*(size_t)N);
  int*   cnt_b   = cnt_f + N;
  int*   ptr_f   = (int*)alloc((size_t)(N+1)*sizeof(int));
  int*   ptr_b   = (int*)alloc((size_t)(N+1)*sizeof(int));
  int*   cur_f   = (int*)alloc((size_t)N*sizeof(int));
  int*   cur_b   = (int*)alloc((size_t)N*sizeof(int));
  int*   col_f   = (int*)alloc((size_t)E*sizeof(int));
  int*   col_b   = (int*)alloc((size_t)E*sizeof(int));
  float* val_f   = (float*)alloc((size_t)E*sizeof(float));
  float* val_b   = (float*)alloc((size_t)E*sizeof(float));
  ushort16* WtG  = (ushort16*)alloc((size_t)2*RUNITS*KP*sizeof(ushort16));
  ushort16* WtC  = (ushort16*)alloc((size_t)RUNITS*KP*sizeof(ushort16));
  ushort16* xsbf = (ushort16*)alloc((size_t)BN*KP*sizeof(ushort16));
  uint32* x0w    = (uint32*)alloc((size_t)N*PW*sizeof(uint32));
  uint32* x1w    = (uint32*)alloc((size_t)N*PW*sizeof(uint32));
  ushort16* rh   = (ushort16*)alloc((size_t)BN*RUNITS*sizeof(ushort16));
  ushort16* ub   = (ushort16*)alloc((size_t)BN*RUNITS*sizeof(ushort16));

  float* out_y = (float*)d_out;
  float* out_h = out_y + BN;

  const int TB = 256;
  int zc = 4*N;
  k_zero_i<<<(zc+TB-1)/TB, TB, 0, stream>>>((int*)deg_out, zc);
  k_deg_cnt<<<(E+TB-1)/TB, TB, 0, stream>>>(esrc, edst, ew, E, deg_out, deg_in, cnt_f, cnt_b);
  k_scan2<<<2, 1024, 0, stream>>>(cnt_f, ptr_f, cur_f, cnt_b, ptr_b, cur_b, N);
  k_fill<<<(E+TB-1)/TB, TB, 0, stream>>>(esrc, edst, ew, E, deg_out, deg_in,
                                         cur_f, cur_b, col_f, val_f, col_b, val_b);
  {
    int tg = 2*RUNITS*KP, tc = RUNITS*KP;
    k_packw<<<(tg+TB-1)/TB, TB, 0, stream>>>(Wg, WtG, 2*RUNITS);
    k_packw<<<(tc+TB-1)/TB, TB, 0, stream>>>(Wc, WtC, RUNITS);
  }

  int sgrid = (N + 3) / 4;
  int gx32  = (BN + 127) / 128;   // gates: 4 waves x 32 rows
  int gx16  = (BN + 63) / 64;     // cand:  4 waves x 16 rows

  // ---- gates gconv ----
  k_build_x0<false><<<N, TB, 0, stream>>>(inputs, hidden, x0w, xsbf, N);
  k_spmm<true ,false><<<sgrid, TB, 0, stream>>>(ptr_f, col_f, val_f, x0w, x0w, x1w, xsbf, N, 1, 1.f,  0.f);
  k_spmm<false,true ><<<sgrid, TB, 0, stream>>>(ptr_f, col_f, val_f, x1w, x0w, x1w, xsbf, N, 2, 2.f, -1.f);
  k_spmm<true ,false><<<sgrid, TB, 0, stream>>>(ptr_b, col_b, val_b, x0w, x0w, x1w, xsbf, N, 3, 1.f,  0.f);
  k_spmm<false,true ><<<sgrid, TB, 0, stream>>>(ptr_b, col_b, val_b, x1w, x0w, x1w, xsbf, N, 4, 2.f, -1.f);
  k_gemm<32, 0><<<dim3(gx32, 4), TB, 0, stream>>>(
      xsbf, WtG, bg, hidden, nullptr, rh, ub, BN);

  // ---- candidate gconv (hx replaced by r*hx, bf16) ----
  k_build_x0<true><<<N, TB, 0, stream>>>(inputs, rh, x0w, xsbf, N);
  k_spmm<true ,false><<<sgrid, TB, 0, stream>>>(ptr_f, col_f, val_f, x0w, x0w, x1w, xsbf, N, 1, 1.f,  0.f);
  k_spmm<false,true ><<<sgrid, TB, 0, stream>>>(ptr_f, col_f, val_f, x1w, x0w, x1w, xsbf, N, 2, 2.f, -1.f);
  k_spmm<true ,false><<<sgrid, TB, 0, stream>>>(ptr_b, col_b, val_b, x0w, x0w, x1w, xsbf, N, 3, 1.f,  0.f);
  k_spmm<false,true ><<<sgrid, TB, 0, stream>>>(ptr_b, col_b, val_b, x1w, x0w, x1w, xsbf, N, 4, 2.f, -1.f);
  k_gemm<16, 1><<<dim3(gx16, 2), TB, 0, stream>>>(
      xsbf, WtC, bc, hidden, ub, out_h, nullptr, BN);

  // ---- projection ----
  k_proj<<<((size_t)BN*64 + TB - 1)/TB, TB, 0, stream>>>(out_h, Wpj, bpj, out_y, BN);
}

// Round 4
// 447.880 us; speedup vs baseline: 2.1115x; 1.2225x over previous
//
#include <hip/hip_runtime.h>
#include <cstdint>
#include <cstddef>

#define BATCH  4
#define RUNITS 128
#define CC     129            // 1 + RUNITS
#define MM     5              // 2*K+1
#define FDIM   516            // BATCH*CC
#define PAIRS  258            // FDIM/2 (uint32 words of 2 bf16)
#define PW     260            // padded row stride in words (1040 B, 16B-aligned)
#define CP     136            // per-m padded channel count
#define KP     704            // padded K' (22*32); real = MM*CP = 680

typedef unsigned int  uint32;
typedef unsigned short ushort16;
typedef __attribute__((ext_vector_type(8))) short short8;
typedef __attribute__((ext_vector_type(4))) float f32x4;

__device__ inline float bflo(uint32 u){ return __uint_as_float(u << 16); }
__device__ inline float bfhi(uint32 u){ return __uint_as_float(u & 0xFFFF0000u); }
__device__ inline ushort16 f2bf(float f){
  uint32 u = __float_as_uint(f);
  return (ushort16)((u + 0x7FFFu + ((u >> 16) & 1u)) >> 16);
}
__device__ inline uint32 packbf(float a, float b){
  return (uint32)f2bf(a) | ((uint32)f2bf(b) << 16);
}
__device__ inline float bf2f(ushort16 v){ return __uint_as_float(((uint32)v) << 16); }

// ---------------- graph prep ----------------

__global__ void k_zero_i(int* p, int n) {
  int i = blockIdx.x*blockDim.x + threadIdx.x;
  if (i < n) p[i] = 0;
}

__global__ void k_deg_cnt(const int* __restrict__ src, const int* __restrict__ dst,
                          const float* __restrict__ w, int E,
                          float* deg_out, float* deg_in, int* cnt_f, int* cnt_b) {
  int e = blockIdx.x*blockDim.x + threadIdx.x;
  if (e >= E) return;
  int s = src[e], d = dst[e]; float we = w[e];
  atomicAdd(&deg_out[s], we);
  atomicAdd(&deg_in[d], we);
  atomicAdd(&cnt_f[s], 1);
  atomicAdd(&cnt_b[d], 1);
}

__global__ __launch_bounds__(1024) void k_scan2(
    const int* __restrict__ cnt_f, int* ptr_f, int* cur_f,
    const int* __restrict__ cnt_b, int* ptr_b, int* cur_b, int n) {
  const int* cnt = (blockIdx.x == 0) ? cnt_f : cnt_b;
  int* ptr = (blockIdx.x == 0) ? ptr_f : ptr_b;
  int* cur = (blockIdx.x == 0) ? cur_f : cur_b;
  __shared__ int sm[1024];
  __shared__ int carry_s;
  int tid = threadIdx.x;
  if (tid == 0) carry_s = 0;
  __syncthreads();
  for (int base = 0; base < n; base += 1024) {
    int i = base + tid;
    int v = (i < n) ? cnt[i] : 0;
    sm[tid] = v;
    __syncthreads();
    int acc = v;
    for (int off = 1; off < 1024; off <<= 1) {
      int t = (tid >= off) ? sm[tid - off] : 0;
      __syncthreads();
      acc += t;
      sm[tid] = acc;
      __syncthreads();
    }
    int carry = carry_s;
    if (i < n) { ptr[i] = carry + acc - v; cur[i] = carry + acc - v; }
    __syncthreads();
    if (tid == 1023) carry_s = carry + sm[1023];
    __syncthreads();
  }
  if (tid == 0) ptr[n] = carry_s;
}

__global__ void k_fill(const int* __restrict__ src, const int* __restrict__ dst,
                       const float* __restrict__ w, int E,
                       const float* __restrict__ deg_out, const float* __restrict__ deg_in,
                       int* cur_f, int* cur_b,
                       int* col_f, float* val_f, int* col_b, float* val_b) {
  int e = blockIdx.x*blockDim.x + threadIdx.x;
  if (e >= E) return;
  int s = src[e], d = dst[e]; float we = w[e];
  int pf = atomicAdd(&cur_f[s], 1);
  col_f[pf] = d; val_f[pf] = we / deg_out[s];
  int pb = atomicAdd(&cur_b[d], 1);
  col_b[pb] = s; val_b[pb] = we / deg_in[d];
}

// ---------------- weight pack: Wt[o][k'=m*CP+c] (bf16, zero pads) ----------------

__global__ void k_packw(const float* __restrict__ W, ushort16* __restrict__ Wt, int ncol) {
  int idx = blockIdx.x*blockDim.x + threadIdx.x;
  int total = ncol * KP;
  if (idx >= total) return;
  int o = idx / KP, k = idx - o*KP;
  int m = k / CP, c = k - m*CP;
  float v = (m < MM && c < CC) ? W[(size_t)(c*MM + m)*ncol + o] : 0.f;
  Wt[idx] = f2bf(v);
}

// ---------------- shared store path: row n, 8 feats/lane -> xw + xsbf ----------------

__device__ inline void store_feats(uint32* __restrict__ xw, ushort16* __restrict__ xsbf,
                                   int n, int N, int lane, int loff,
                                   const float r[8]) {
  uint4 ov;
  ov.x = packbf(r[0], r[1]); ov.y = packbf(r[2], r[3]);
  ov.z = packbf(r[4], r[5]); ov.w = packbf(r[6], r[7]);
  *(uint4*)(xw + (size_t)n*PW + 4*lane) = ov;
  int f0 = 8*lane;
  int b0 = f0 / CC, c0 = f0 - b0*CC;
  if (c0 <= CC - 8) {
    short8 pk;
    #pragma unroll
    for (int s2 = 0; s2 < 8; ++s2) pk[s2] = (short)f2bf(r[s2]);
    *(short8*)&xsbf[((size_t)b0*N + n)*KP + loff + c0] = pk;
  } else {
    #pragma unroll
    for (int s2 = 0; s2 < 8; ++s2) {
      int f = f0 + s2; int b = f / CC; int c2 = f - b*CC;
      xsbf[((size_t)b*N + n)*KP + loff + c2] = f2bf(r[s2]);
    }
  }
}

__device__ inline void store_tail(uint32* __restrict__ xw, ushort16* __restrict__ xsbf,
                                  int n, int N, int lane, int loff, float q0, float q1) {
  // lane < 2 only; features 512 + 2*lane (b=3, c=125..128)
  xw[(size_t)n*PW + 256 + lane] = packbf(q0, q1);
  int c2 = 512 + 2*lane - 3*CC;
  xsbf[((size_t)3*N + n)*KP + loff + c2]     = f2bf(q0);
  xsbf[((size_t)3*N + n)*KP + loff + c2 + 1] = f2bf(q1);
}

// ---------------- feature assembly (wave per node) ----------------

template<bool HBF>
__global__ __launch_bounds__(256) void k_build_x0(
    const float* __restrict__ inp, const void* __restrict__ hsrc,
    uint32* __restrict__ xw, ushort16* __restrict__ xsbf, int N) {
  int wv = threadIdx.x >> 6, lane = threadIdx.x & 63;
  int n = blockIdx.x*4 + wv;
  if (n >= N) return;
  const float* hf = (const float*)hsrc;
  const ushort16* hb = (const ushort16*)hsrc;
  float r[8];
  int f0 = 8*lane;
  #pragma unroll
  for (int s = 0; s < 8; ++s) {
    int f = f0 + s;
    int b = f / CC, c = f - b*CC;
    size_t rr = (size_t)b*N + n;
    float x;
    if (c == 0) x = inp[rr];
    else {
      size_t hi = rr*RUNITS + (c-1);
      x = HBF ? bf2f(hb[hi]) : hf[hi];
    }
    r[s] = x;
  }
  store_feats(xw, xsbf, n, N, lane, 0, r);
  if (lane < 2) {
    int f = 512 + 2*lane;
    int c = f - 3*CC;             // 125..128 (c in [1..128] here)
    size_t rr = (size_t)3*N + n;
    float q0 = HBF ? bf2f(hb[rr*RUNITS + (c-1)]) : hf[rr*RUNITS + (c-1)];
    float q1;
    int c1 = c + 1;
    q1 = HBF ? bf2f(hb[rr*RUNITS + (c1-1)]) : hf[rr*RUNITS + (c1-1)];
    store_tail(xw, xsbf, n, N, lane, 0, q0, q1);
  }
}

// ---------------- SPMM: wave-per-row; out = alpha*sum(val*X[col]) + beta*Y ----------------

template<bool WW, bool HY>
__global__ __launch_bounds__(256) void k_spmm(
    const int* __restrict__ ptr, const int* __restrict__ col, const float* __restrict__ val,
    const uint32* __restrict__ X, const uint32* __restrict__ Y,
    uint32* __restrict__ Xout, ushort16* __restrict__ xsbf,
    int N, int level, float alpha, float beta) {
  int wv = threadIdx.x >> 6, lane = threadIdx.x & 63;
  int n = blockIdx.x*4 + wv;
  if (n >= N) return;
  int s = ptr[n], e = ptr[n+1];
  const int wl = 4*lane;
  float a[8] = {0.f,0.f,0.f,0.f,0.f,0.f,0.f,0.f};
  float t0 = 0.f, t1 = 0.f;
  #pragma unroll 4
  for (int i = s; i < e; ++i) {
    int c = col[i]; float v = val[i];
    const uint32* Xr = X + (size_t)c*PW;
    uint4 u = *(const uint4*)(Xr + wl);
    a[0] += v*bflo(u.x); a[1] += v*bfhi(u.x);
    a[2] += v*bflo(u.y); a[3] += v*bfhi(u.y);
    a[4] += v*bflo(u.z); a[5] += v*bfhi(u.z);
    a[6] += v*bflo(u.w); a[7] += v*bfhi(u.w);
    if (lane < 2) { uint32 uw = Xr[256+lane]; t0 += v*bflo(uw); t1 += v*bfhi(uw); }
  }
  float r[8];
  if (HY) {
    uint4 yv = *(const uint4*)(Y + (size_t)n*PW + wl);
    r[0] = alpha*a[0] + beta*bflo(yv.x); r[1] = alpha*a[1] + beta*bfhi(yv.x);
    r[2] = alpha*a[2] + beta*bflo(yv.y); r[3] = alpha*a[3] + beta*bfhi(yv.y);
    r[4] = alpha*a[4] + beta*bflo(yv.z); r[5] = alpha*a[5] + beta*bfhi(yv.z);
    r[6] = alpha*a[6] + beta*bflo(yv.w); r[7] = alpha*a[7] + beta*bfhi(yv.w);
  } else {
    #pragma unroll
    for (int s2 = 0; s2 < 8; ++s2) r[s2] = alpha*a[s2];
  }
  int loff = level*CP;
  if (WW) {
    store_feats(Xout, xsbf, n, N, lane, loff, r);
  } else {
    // no Xout write: still need xsbf scatter (reuse path with dummy? write xw too costly)
    int f0 = 8*lane;
    int b0 = f0 / CC, c0 = f0 - b0*CC;
    if (c0 <= CC - 8) {
      short8 pk;
      #pragma unroll
      for (int s2 = 0; s2 < 8; ++s2) pk[s2] = (short)f2bf(r[s2]);
      *(short8*)&xsbf[((size_t)b0*N + n)*KP + loff + c0] = pk;
    } else {
      #pragma unroll
      for (int s2 = 0; s2 < 8; ++s2) {
        int f = f0 + s2; int b = f / CC; int c2 = f - b*CC;
        xsbf[((size_t)b*N + n)*KP + loff + c2] = f2bf(r[s2]);
      }
    }
  }
  if (lane < 2) {
    float q0, q1;
    if (HY) {
      uint32 yw = Y[(size_t)n*PW + 256 + lane];
      q0 = alpha*t0 + beta*bflo(yw); q1 = alpha*t1 + beta*bfhi(yw);
    } else { q0 = alpha*t0; q1 = alpha*t1; }
    if (WW) {
      store_tail(Xout, xsbf, n, N, lane, loff, q0, q1);
    } else {
      int c2 = 512 + 2*lane - 3*CC;
      xsbf[((size_t)3*N + n)*KP + loff + c2]     = f2bf(q0);
      xsbf[((size_t)3*N + n)*KP + loff + c2 + 1] = f2bf(q1);
    }
  }
}

// ---------------- MFMA GEMM, LDS double-buffered, 1 barrier/step ----------------
// block 512 thr (8 waves). tile TM=NI*64 rows x 128 cols.
// wave (wm=wv>>1, wn=wv&1): wave-tile (NI*16) rows x 64 cols.
// MODE 0 (gates): s=sigmoid(g); o<128 -> rh(bf16)=s*hx ; o>=128 -> u(bf16)=s
// MODE 1 (cand):  c=tanh(g);  out_h(f32) = u*hx + (1-u)*c

template<int NI, int MODE>
__global__ __launch_bounds__(512, 4) void k_gemm(
    const ushort16* __restrict__ A, const ushort16* __restrict__ Bt,
    const float* __restrict__ bias, const float* __restrict__ hx,
    const ushort16* __restrict__ uin, void* __restrict__ out0,
    ushort16* __restrict__ out1, int BN) {
  constexpr int TM = NI * 64;
  constexpr int NK = KP / 32;
  __shared__ ushort16 As[2][TM][40];    // stride 80B: frag reads 2-way (free)
  __shared__ ushort16 Bs[2][128][40];
  int tid = threadIdx.x;
  int lane = tid & 63, wv = tid >> 6;
  int wm = wv >> 1, wn = wv & 1;
  int fr = lane & 15, g = lane >> 4;
  int R0 = blockIdx.x * TM;
  int O0 = blockIdx.y * 128;

  // staging: 16B per thread for B (128x32), A full (NI=2) or half threads (NI=1)
  int sr = tid >> 2, sh = (tid & 3) * 8;
  const ushort16* Bp = Bt + (size_t)(O0 + sr)*KP + sh;
  bool aact = (NI == 2) ? true : (tid < 256);
  int arow = R0 + sr; if (arow >= BN) arow = BN - 1;
  const ushort16* Ap = A + (size_t)arow*KP + sh;

  uint4 ra, rb;
  rb = *(const uint4*)Bp;
  if (aact) ra = *(const uint4*)Ap;

  f32x4 acc[NI][4];
  #pragma unroll
  for (int i = 0; i < NI; ++i)
    #pragma unroll
    for (int j = 0; j < 4; ++j)
      acc[i][j] = (f32x4){0.f,0.f,0.f,0.f};

  int buf = 0;
  for (int kt = 0; kt < NK; ++kt) {
    if (aact) *(uint4*)&As[buf][sr][sh] = ra;
    *(uint4*)&Bs[buf][sr][sh] = rb;
    __syncthreads();
    if (kt + 1 < NK) {
      rb = *(const uint4*)(Bp + (kt+1)*32);
      if (aact) ra = *(const uint4*)(Ap + (kt+1)*32);
    }
    short8 af[NI], bf[4];
    #pragma unroll
    for (int i = 0; i < NI; ++i)
      af[i] = *(const short8*)&As[buf][wm*(NI*16) + i*16 + fr][g*8];
    #pragma unroll
    for (int j = 0; j < 4; ++j)
      bf[j] = *(const short8*)&Bs[buf][wn*64 + j*16 + fr][g*8];
    #pragma unroll
    for (int i = 0; i < NI; ++i)
      #pragma unroll
      for (int j = 0; j < 4; ++j)
        acc[i][j] = __builtin_amdgcn_mfma_f32_16x16x32_bf16(af[i], bf[j], acc[i][j], 0, 0, 0);
    buf ^= 1;
  }

  #pragma unroll
  for (int i = 0; i < NI; ++i) {
    #pragma unroll
    for (int q = 0; q < 4; ++q) {
      int row = R0 + wm*(NI*16) + i*16 + g*4 + q;
      if (row >= BN) continue;
      #pragma unroll
      for (int j = 0; j < 4; ++j) {
        int o = O0 + wn*64 + j*16 + fr;
        float gv = acc[i][j][q] + bias[o];
        if (MODE == 0) {
          float sg = 1.f/(1.f + expf(-gv));
          if (o < RUNITS)
            ((ushort16*)out0)[(size_t)row*RUNITS + o] = f2bf(sg * hx[(size_t)row*RUNITS + o]);
          else
            out1[(size_t)row*RUNITS + (o - RUNITS)] = f2bf(sg);
        } else {
          float cv = tanhf(gv);
          float uu = bf2f(uin[(size_t)row*RUNITS + o]);
          float hh = hx[(size_t)row*RUNITS + o];
          ((float*)out0)[(size_t)row*RUNITS + o] = uu*hh + (1.f - uu)*cv;
        }
      }
    }
  }
}

// ---------------- projection ----------------

__global__ void k_proj(const float* __restrict__ nh, const float* __restrict__ w,
                       const float* __restrict__ bp, float* __restrict__ out, int rows) {
  int gwid = (int)((blockIdx.x*(size_t)blockDim.x + threadIdx.x) >> 6);
  int lane = threadIdx.x & 63;
  if (gwid >= rows) return;
  const float* r = nh + (size_t)gwid*RUNITS;
  float s = r[lane]*w[lane] + r[lane+64]*w[lane+64];
  #pragma unroll
  for (int off = 32; off > 0; off >>= 1) s += __shfl_down(s, off);
  if (lane == 0) out[gwid] = s + bp[0];
}

// ---------------- launcher ----------------

extern "C" void kernel_launch(void* const* d_in, const int* in_sizes, int n_in,
                              void* d_out, int out_size, void* d_ws, size_t ws_size,
                              hipStream_t stream) {
  const float* inputs = (const float*)d_in[0];
  const float* hidden = (const float*)d_in[1];
  const int*   esrc   = (const int*)d_in[2];
  const int*   edst   = (const int*)d_in[3];
  const float* ew     = (const float*)d_in[4];
  const float* Wg     = (const float*)d_in[5];
  const float* bg     = (const float*)d_in[6];
  const float* Wc     = (const float*)d_in[7];
  const float* bc     = (const float*)d_in[8];
  const float* Wpj    = (const float*)d_in[9];
  const float* bpj    = (const float*)d_in[10];

  const int N  = in_sizes[0] / BATCH;
  const int E  = in_sizes[2];
  const int BN = BATCH * N;

  char* p = (char*)d_ws;
  auto alloc = [&](size_t bytes) -> void* {
    void* r = (void*)p;
    p += (bytes + 255) & ~(size_t)255;
    return r;
  };

  float* deg_out = (float*)alloc((size_t)4*N*sizeof(float));
  float* deg_in  = deg_out + N;
  int*   cnt_f   = (int*)(deg_out + 2*(size_t)N);
  int*   cnt_b   = cnt_f + N;
  int*   ptr_f   = (int*)alloc((size_t)(N+1)*sizeof(int));
  int*   ptr_b   = (int*)alloc((size_t)(N+1)*sizeof(int));
  int*   cur_f   = (int*)alloc((size_t)N*sizeof(int));
  int*   cur_b   = (int*)alloc((size_t)N*sizeof(int));
  int*   col_f   = (int*)alloc((size_t)E*sizeof(int));
  int*   col_b   = (int*)alloc((size_t)E*sizeof(int));
  float* val_f   = (float*)alloc((size_t)E*sizeof(float));
  float* val_b   = (float*)alloc((size_t)E*sizeof(float));
  ushort16* WtG  = (ushort16*)alloc((size_t)2*RUNITS*KP*sizeof(ushort16));
  ushort16* WtC  = (ushort16*)alloc((size_t)RUNITS*KP*sizeof(ushort16));
  ushort16* xsbf = (ushort16*)alloc((size_t)BN*KP*sizeof(ushort16));
  uint32* x0w    = (uint32*)alloc((size_t)N*PW*sizeof(uint32));
  uint32* x1w    = (uint32*)alloc((size_t)N*PW*sizeof(uint32));
  ushort16* rh   = (ushort16*)alloc((size_t)BN*RUNITS*sizeof(ushort16));
  ushort16* ub   = (ushort16*)alloc((size_t)BN*RUNITS*sizeof(ushort16));

  float* out_y = (float*)d_out;
  float* out_h = out_y + BN;

  const int TB = 256;
  int zc = 4*N;
  k_zero_i<<<(zc+TB-1)/TB, TB, 0, stream>>>((int*)deg_out, zc);
  k_deg_cnt<<<(E+TB-1)/TB, TB, 0, stream>>>(esrc, edst, ew, E, deg_out, deg_in, cnt_f, cnt_b);
  k_scan2<<<2, 1024, 0, stream>>>(cnt_f, ptr_f, cur_f, cnt_b, ptr_b, cur_b, N);
  k_fill<<<(E+TB-1)/TB, TB, 0, stream>>>(esrc, edst, ew, E, deg_out, deg_in,
                                         cur_f, cur_b, col_f, val_f, col_b, val_b);
  {
    int tg = 2*RUNITS*KP, tc = RUNITS*KP;
    k_packw<<<(tg+TB-1)/TB, TB, 0, stream>>>(Wg, WtG, 2*RUNITS);
    k_packw<<<(tc+TB-1)/TB, TB, 0, stream>>>(Wc, WtC, RUNITS);
  }

  int sgrid = (N + 3) / 4;
  int gxg = (BN + 127) / 128;     // gates: TM=128
  int gxc = (BN + 63) / 64;       // cand:  TM=64

  // ---- gates gconv ----
  k_build_x0<false><<<sgrid, TB, 0, stream>>>(inputs, hidden, x0w, xsbf, N);
  k_spmm<true ,false><<<sgrid, TB, 0, stream>>>(ptr_f, col_f, val_f, x0w, x0w, x1w, xsbf, N, 1, 1.f,  0.f);
  k_spmm<false,true ><<<sgrid, TB, 0, stream>>>(ptr_f, col_f, val_f, x1w, x0w, x1w, xsbf, N, 2, 2.f, -1.f);
  k_spmm<true ,false><<<sgrid, TB, 0, stream>>>(ptr_b, col_b, val_b, x0w, x0w, x1w, xsbf, N, 3, 1.f,  0.f);
  k_spmm<false,true ><<<sgrid, TB, 0, stream>>>(ptr_b, col_b, val_b, x1w, x0w, x1w, xsbf, N, 4, 2.f, -1.f);
  k_gemm<2, 0><<<dim3(gxg, 2), 512, 0, stream>>>(
      xsbf, WtG, bg, hidden, nullptr, rh, ub, BN);

  // ---- candidate gconv (hx replaced by r*hx, bf16) ----
  k_build_x0<true><<<sgrid, TB, 0, stream>>>(inputs, rh, x0w, xsbf, N);
  k_spmm<true ,false><<<sgrid, TB, 0, stream>>>(ptr_f, col_f, val_f, x0w, x0w, x1w, xsbf, N, 1, 1.f,  0.f);
  k_spmm<false,true ><<<sgrid, TB, 0, stream>>>(ptr_f, col_f, val_f, x1w, x0w, x1w, xsbf, N, 2, 2.f, -1.f);
  k_spmm<true ,false><<<sgrid, TB, 0, stream>>>(ptr_b, col_b, val_b, x0w, x0w, x1w, xsbf, N, 3, 1.f,  0.f);
  k_spmm<false,true ><<<sgrid, TB, 0, stream>>>(ptr_b, col_b, val_b, x1w, x0w, x1w, xsbf, N, 4, 2.f, -1.f);
  k_gemm<1, 1><<<dim3(gxc, 1), 512, 0, stream>>>(
      xsbf, WtC, bc, hidden, ub, out_h, nullptr, BN);

  // ---- projection ----
  k_proj<<<((size_t)BN*64 + TB - 1)/TB, TB, 0, stream>>>(out_h, Wpj, bpj, out_y, BN);
}

// Round 5
// 402.073 us; speedup vs baseline: 2.3521x; 1.1139x over previous
//
#include <hip/hip_runtime.h>
#include <cstdint>
#include <cstddef>

#define BATCH  4
#define RUNITS 128
#define CC     129            // 1 + RUNITS
#define MM     5
#define SEG    136            // ushorts per b-segment (c 0..128 real, 129..135 zero)
#define US     544            // ushorts per node row = 4*SEG (1088B)
#define KB     672            // GEMM K: 20 steps of 32 (c<128) + 1 step (c==128 x 5m)
#define NSTEP  21

typedef unsigned int  uint32;
typedef unsigned short ushort16;
typedef __attribute__((ext_vector_type(8))) short short8;
typedef __attribute__((ext_vector_type(4))) float f32x4;

__device__ inline float bflo(uint32 u){ return __uint_as_float(u << 16); }
__device__ inline float bfhi(uint32 u){ return __uint_as_float(u & 0xFFFF0000u); }
__device__ inline ushort16 f2bf(float f){
  uint32 u = __float_as_uint(f);
  return (ushort16)((u + 0x7FFFu + ((u >> 16) & 1u)) >> 16);
}
__device__ inline float bf2f(ushort16 v){ return __uint_as_float(((uint32)v) << 16); }

// ---------------- graph prep ----------------

__global__ void k_zero_i(int* p, int n) {
  int i = blockIdx.x*blockDim.x + threadIdx.x;
  if (i < n) p[i] = 0;
}

__global__ void k_deg_cnt(const int* __restrict__ src, const int* __restrict__ dst,
                          const float* __restrict__ w, int E,
                          float* deg_out, float* deg_in, int* cnt_f, int* cnt_b) {
  int e = blockIdx.x*blockDim.x + threadIdx.x;
  if (e >= E) return;
  int s = src[e], d = dst[e]; float we = w[e];
  atomicAdd(&deg_out[s], we);
  atomicAdd(&deg_in[d], we);
  atomicAdd(&cnt_f[s], 1);
  atomicAdd(&cnt_b[d], 1);
}

// 3-phase scan, 40 blocks x 256
__global__ __launch_bounds__(256) void k_scansum(
    const int* __restrict__ cnt_f, const int* __restrict__ cnt_b, int* bsum, int n) {
  const int* cnt = blockIdx.y ? cnt_b : cnt_f;
  int tid = threadIdx.x, lane = tid & 63, wv = tid >> 6;
  int i = blockIdx.x*256 + tid;
  int v = (i < n) ? cnt[i] : 0;
  #pragma unroll
  for (int d = 32; d > 0; d >>= 1) v += __shfl_down(v, d);
  __shared__ int sm[4];
  if (lane == 0) sm[wv] = v;
  __syncthreads();
  if (tid == 0) bsum[blockIdx.y*40 + blockIdx.x] = sm[0]+sm[1]+sm[2]+sm[3];
}

__global__ __launch_bounds__(64) void k_scanmid(
    const int* bsum, int* bofs, int* ptrF, int* ptrB, int n, int nb) {
  int lane = threadIdx.x;
  for (int a = 0; a < 2; ++a) {
    int v = (lane < nb) ? bsum[a*nb + lane] : 0;
    int x = v;
    #pragma unroll
    for (int d = 1; d < 64; d <<= 1) { int t = __shfl_up(x, d); if (lane >= d) x += t; }
    if (lane < nb) bofs[a*nb + lane] = x - v;
    if (lane == nb - 1) { if (a) ptrB[n] = x; else ptrF[n] = x; }
  }
}

__global__ __launch_bounds__(256) void k_scanapply(
    const int* __restrict__ cnt_f, const int* __restrict__ cnt_b, const int* __restrict__ bofs,
    int* ptrF, int* curF, int* ptrB, int* curB, int n) {
  int a = blockIdx.y;
  const int* cnt = a ? cnt_b : cnt_f;
  int* ptr = a ? ptrB : ptrF;
  int* cur = a ? curB : curF;
  int tid = threadIdx.x, lane = tid & 63, wv = tid >> 6;
  int i = blockIdx.x*256 + tid;
  int v = (i < n) ? cnt[i] : 0;
  int x = v;
  #pragma unroll
  for (int d = 1; d < 64; d <<= 1) { int t = __shfl_up(x, d); if (lane >= d) x += t; }
  __shared__ int ws[4];
  __shared__ int wo[4];
  if (lane == 63) ws[wv] = x;
  __syncthreads();
  if (tid == 0) { int s = 0; for (int k = 0; k < 4; ++k) { wo[k] = s; s += ws[k]; } }
  __syncthreads();
  int excl = x - v + wo[wv] + bofs[a*40 + blockIdx.x];
  if (i < n) { ptr[i] = excl; cur[i] = excl; }
}

__global__ void k_fill(const int* __restrict__ src, const int* __restrict__ dst,
                       const float* __restrict__ w, int E,
                       const float* __restrict__ deg_out, const float* __restrict__ deg_in,
                       int* cur_f, int* cur_b,
                       int* col_f, float* val_f, int* col_b, float* val_b) {
  int e = blockIdx.x*blockDim.x + threadIdx.x;
  if (e >= E) return;
  int s = src[e], d = dst[e]; float we = w[e];
  int pf = atomicAdd(&cur_f[s], 1);
  col_f[pf] = d; val_f[pf] = we / deg_out[s];
  int pb = atomicAdd(&cur_b[d], 1);
  col_b[pb] = s; val_b[pb] = we / deg_in[d];
}

// ---------------- weight pack: Bt[o][k], K=672 layout ----------------
// k = s*32+j: s<20: m=s>>2, c=(s&3)*32+j -> W[(c*5+m)*ncol+o]
//             s==20: j<5 -> W[(128*5+j)*ncol+o] else 0

__global__ void k_packw(const float* __restrict__ W, ushort16* __restrict__ Bt, int ncol) {
  int idx = blockIdx.x*blockDim.x + threadIdx.x;
  int total = ncol * KB;
  if (idx >= total) return;
  int o = idx / KB, k = idx - o*KB;
  int s = k >> 5, j = k & 31;
  float v = 0.f;
  if (s < 20) {
    int m = s >> 2, c = (s & 3)*32 + j;
    v = W[(size_t)(c*MM + m)*ncol + o];
  } else if (j < MM) {
    v = W[(size_t)(RUNITS*MM + j)*ncol + o];
  }
  Bt[idx] = f2bf(v);
}

// ---------------- build x0: xall level 0 (zero pads) ----------------

template<bool HBF>
__global__ __launch_bounds__(256) void k_build_x0(
    const float* __restrict__ inp, const void* __restrict__ hsrc,
    ushort16* __restrict__ x0, int N) {
  int wv = threadIdx.x >> 6, lane = threadIdx.x & 63;
  int n = blockIdx.x*4 + wv;
  if (n >= N) return;
  const float* hf = (const float*)hsrc;
  const ushort16* hb = (const ushort16*)hsrc;
  size_t ob = (size_t)n*US;
  for (int ch = lane; ch < 68; ch += 64) {
    int b = ch / 17, l = ch - b*17;
    size_t r = (size_t)b*N + n;
    short8 pk;
    #pragma unroll
    for (int s = 0; s < 8; ++s) {
      int c = l*8 + s;
      float x = 0.f;
      if (c == 0) x = inp[r];
      else if (c <= RUNITS) x = HBF ? bf2f(hb[r*RUNITS + (c-1)]) : hf[r*RUNITS + (c-1)];
      pk[s] = (short)f2bf(x);
    }
    *(short8*)&x0[ob + ch*8] = pk;
  }
}

// ---------------- fused dual SPMM: out = alpha*sum(val*X[col]) + beta*Y0 ----------------

template<bool HY>
__global__ __launch_bounds__(256) void k_spmm2(
    const int* __restrict__ ptrF, const int* __restrict__ colF, const float* __restrict__ valF,
    const ushort16* __restrict__ XF, ushort16* __restrict__ outF,
    const int* __restrict__ ptrB, const int* __restrict__ colB, const float* __restrict__ valB,
    const ushort16* __restrict__ XB, ushort16* __restrict__ outB,
    const ushort16* __restrict__ Y0, int N, int sgrid, float alpha, float beta) {
  int bid = blockIdx.x;
  bool jb = bid >= sgrid;
  const int* ptr = jb ? ptrB : ptrF;
  const int* col = jb ? colB : colF;
  const float* val = jb ? valB : valF;
  const ushort16* X = jb ? XB : XF;
  ushort16* out = jb ? outB : outF;
  int wv = threadIdx.x >> 6, lane = threadIdx.x & 63;
  int n = (bid - (jb ? sgrid : 0))*4 + wv;
  if (n >= N) return;
  int s = ptr[n], e = ptr[n+1];
  int ch0 = lane*8, ch1 = (64+lane)*8;
  bool t4 = lane < 4;
  float a0[8] = {0,0,0,0,0,0,0,0};
  float a1[8] = {0,0,0,0,0,0,0,0};
  #pragma unroll 2
  for (int i = s; i < e; ++i) {
    int c = col[i]; float v = val[i];
    const ushort16* Xr = X + (size_t)c*US;
    uint4 u = *(const uint4*)(Xr + ch0);
    a0[0] += v*bflo(u.x); a0[1] += v*bfhi(u.x);
    a0[2] += v*bflo(u.y); a0[3] += v*bfhi(u.y);
    a0[4] += v*bflo(u.z); a0[5] += v*bfhi(u.z);
    a0[6] += v*bflo(u.w); a0[7] += v*bfhi(u.w);
    if (t4) {
      uint4 u2 = *(const uint4*)(Xr + ch1);
      a1[0] += v*bflo(u2.x); a1[1] += v*bfhi(u2.x);
      a1[2] += v*bflo(u2.y); a1[3] += v*bfhi(u2.y);
      a1[4] += v*bflo(u2.z); a1[5] += v*bfhi(u2.z);
      a1[6] += v*bflo(u2.w); a1[7] += v*bfhi(u2.w);
    }
  }
  size_t ob = (size_t)n*US;
  {
    float r[8];
    if (HY) {
      uint4 y = *(const uint4*)(Y0 + ob + ch0);
      r[0] = alpha*a0[0] + beta*bflo(y.x); r[1] = alpha*a0[1] + beta*bfhi(y.x);
      r[2] = alpha*a0[2] + beta*bflo(y.y); r[3] = alpha*a0[3] + beta*bfhi(y.y);
      r[4] = alpha*a0[4] + beta*bflo(y.z); r[5] = alpha*a0[5] + beta*bfhi(y.z);
      r[6] = alpha*a0[6] + beta*bflo(y.w); r[7] = alpha*a0[7] + beta*bfhi(y.w);
    } else {
      #pragma unroll
      for (int q = 0; q < 8; ++q) r[q] = alpha*a0[q];
    }
    short8 pk;
    #pragma unroll
    for (int q = 0; q < 8; ++q) pk[q] = (short)f2bf(r[q]);
    *(short8*)&out[ob + ch0] = pk;
  }
  if (t4) {
    float r[8];
    if (HY) {
      uint4 y = *(const uint4*)(Y0 + ob + ch1);
      r[0] = alpha*a1[0] + beta*bflo(y.x); r[1] = alpha*a1[1] + beta*bfhi(y.x);
      r[2] = alpha*a1[2] + beta*bflo(y.y); r[3] = alpha*a1[3] + beta*bfhi(y.y);
      r[4] = alpha*a1[4] + beta*bflo(y.z); r[5] = alpha*a1[5] + beta*bfhi(y.z);
      r[6] = alpha*a1[6] + beta*bflo(y.w); r[7] = alpha*a1[7] + beta*bfhi(y.w);
    } else {
      #pragma unroll
      for (int q = 0; q < 8; ++q) r[q] = alpha*a1[q];
    }
    short8 pk;
    #pragma unroll
    for (int q = 0; q < 8; ++q) pk[q] = (short)f2bf(r[q]);
    *(short8*)&out[ob + ch1] = pk;
  }
}

// ---------------- gates GEMM: tile 64x128, 4 waves (16x128 each), grid (BN/64, 2) ----------------

__global__ __launch_bounds__(256) void k_gemm_g(
    const ushort16* __restrict__ xall, const ushort16* __restrict__ Bt,
    const float* __restrict__ bias, const float* __restrict__ hx,
    ushort16* __restrict__ rh, ushort16* __restrict__ ub, int N, int BN) {
  __shared__ ushort16 As[2][64][40];
  __shared__ ushort16 Bs[2][128][40];
  int tid = threadIdx.x, lane = tid & 63, wv = tid >> 6;
  int fr = lane & 15, g = lane >> 4;
  int R0 = blockIdx.x*64, by = blockIdx.y;
  const ushort16* BtP = Bt + (size_t)by*128*KB;

  int rowA = tid >> 2, qA = tid & 3;
  int gr = R0 + rowA; if (gr >= BN) gr = BN - 1;
  int bA = gr / N, nA = gr - bA*N;
  const size_t mstride = (size_t)N*US;
  const ushort16* aPt = xall + (size_t)nA*US + bA*SEG + qA*8;

  int colB = tid >> 2, qB = tid & 3;
  const ushort16* bPt0 = BtP + (size_t)colB*KB + qB*8;
  const ushort16* bPt1 = BtP + (size_t)(colB+64)*KB + qB*8;

  f32x4 acc[8];
  #pragma unroll
  for (int j = 0; j < 8; ++j) acc[j] = (f32x4){0.f,0.f,0.f,0.f};

  uint4 ra, rb0, rb1;
  {
    ra  = *(const uint4*)(aPt);
    rb0 = *(const uint4*)(bPt0);
    rb1 = *(const uint4*)(bPt1);
  }
  int buf = 0;
  for (int s = 0; s < 20; ++s) {
    *(uint4*)&As[buf][rowA][qA*8] = ra;
    *(uint4*)&Bs[buf][colB][qB*8] = rb0;
    *(uint4*)&Bs[buf][colB+64][qB*8] = rb1;
    __syncthreads();
    if (s < 19) {
      int s1 = s + 1;
      int m = s1 >> 2, cb = (s1 & 3)*32;
      ra  = *(const uint4*)(aPt + (size_t)m*mstride + cb);
      rb0 = *(const uint4*)(bPt0 + s1*32);
      rb1 = *(const uint4*)(bPt1 + s1*32);
    }
    short8 af = *(const short8*)&As[buf][wv*16 + fr][g*8];
    short8 bf[8];
    #pragma unroll
    for (int j = 0; j < 8; ++j) bf[j] = *(const short8*)&Bs[buf][j*16 + fr][g*8];
    #pragma unroll
    for (int j = 0; j < 8; ++j)
      acc[j] = __builtin_amdgcn_mfma_f32_16x16x32_bf16(af, bf[j], acc[j], 0, 0, 0);
    buf ^= 1;
  }
  // tail step s=20 (c==128 channel for all 5 levels)
  {
    rb0 = *(const uint4*)(bPt0 + 20*32);
    rb1 = *(const uint4*)(bPt1 + 20*32);
    *(uint4*)&Bs[buf][colB][qB*8] = rb0;
    *(uint4*)&Bs[buf][colB+64][qB*8] = rb1;
    if (tid < 64) {
      int row = tid, gr2 = R0 + row; if (gr2 >= BN) gr2 = BN - 1;
      int b2 = gr2 / N, n2 = gr2 - b2*N;
      const ushort16* base = xall + (size_t)n2*US + b2*SEG + 128;
      short8 v = {0,0,0,0,0,0,0,0};
      #pragma unroll
      for (int m = 0; m < MM; ++m) v[m] = (short)base[(size_t)m*mstride];
      short8 z = {0,0,0,0,0,0,0,0};
      *(short8*)&As[buf][row][0]  = v;
      *(short8*)&As[buf][row][8]  = z;
      *(short8*)&As[buf][row][16] = z;
      *(short8*)&As[buf][row][24] = z;
    }
    __syncthreads();
    short8 af = *(const short8*)&As[buf][wv*16 + fr][g*8];
    short8 bf[8];
    #pragma unroll
    for (int j = 0; j < 8; ++j) bf[j] = *(const short8*)&Bs[buf][j*16 + fr][g*8];
    #pragma unroll
    for (int j = 0; j < 8; ++j)
      acc[j] = __builtin_amdgcn_mfma_f32_16x16x32_bf16(af, bf[j], acc[j], 0, 0, 0);
  }
  // epilogue
  #pragma unroll
  for (int q = 0; q < 4; ++q) {
    int row = R0 + wv*16 + g*4 + q;
    if (row >= BN) continue;
    #pragma unroll
    for (int j = 0; j < 8; ++j) {
      int o = by*128 + j*16 + fr;
      float gv = acc[j][q] + bias[o];
      float sg = 1.f/(1.f + expf(-gv));
      if (by == 0)
        rh[(size_t)row*RUNITS + o] = f2bf(sg * hx[(size_t)row*RUNITS + o]);
      else
        ub[(size_t)row*RUNITS + (o - RUNITS)] = f2bf(sg);
    }
  }
}

// ---------------- cand GEMM: tile 32x128, 4 waves (16x64), grid (BN/32, 1), fused GRU+proj ----------------

__global__ __launch_bounds__(256) void k_gemm_c(
    const ushort16* __restrict__ xall, const ushort16* __restrict__ Bt,
    const float* __restrict__ bias, const float* __restrict__ hx,
    const ushort16* __restrict__ ub, float* __restrict__ outh,
    float* __restrict__ outy, const float* __restrict__ wpj, int N, int BN) {
  __shared__ ushort16 As[2][32][40];
  __shared__ ushort16 Bs[2][128][40];
  int tid = threadIdx.x, lane = tid & 63, wv = tid >> 6;
  int wm = wv >> 1, wn = wv & 1;
  int fr = lane & 15, g = lane >> 4;
  int R0 = blockIdx.x*32;

  int rowA = tid >> 2, qA = tid & 3;
  bool aact = tid < 128;
  int gr = R0 + rowA; if (gr >= BN) gr = BN - 1;
  int bA = gr / N, nA = gr - bA*N;
  const size_t mstride = (size_t)N*US;
  const ushort16* aPt = xall + (size_t)nA*US + bA*SEG + qA*8;

  int colB = tid >> 2, qB = tid & 3;
  const ushort16* bPt0 = Bt + (size_t)colB*KB + qB*8;
  const ushort16* bPt1 = Bt + (size_t)(colB+64)*KB + qB*8;

  f32x4 acc[4];
  #pragma unroll
  for (int j = 0; j < 4; ++j) acc[j] = (f32x4){0.f,0.f,0.f,0.f};

  uint4 ra, rb0, rb1;
  if (aact) ra = *(const uint4*)(aPt);
  rb0 = *(const uint4*)(bPt0);
  rb1 = *(const uint4*)(bPt1);

  int buf = 0;
  for (int s = 0; s < 20; ++s) {
    if (aact) *(uint4*)&As[buf][rowA][qA*8] = ra;
    *(uint4*)&Bs[buf][colB][qB*8] = rb0;
    *(uint4*)&Bs[buf][colB+64][qB*8] = rb1;
    __syncthreads();
    if (s < 19) {
      int s1 = s + 1;
      int m = s1 >> 2, cb = (s1 & 3)*32;
      if (aact) ra = *(const uint4*)(aPt + (size_t)m*mstride + cb);
      rb0 = *(const uint4*)(bPt0 + s1*32);
      rb1 = *(const uint4*)(bPt1 + s1*32);
    }
    short8 af = *(const short8*)&As[buf][wm*16 + fr][g*8];
    short8 bf[4];
    #pragma unroll
    for (int j = 0; j < 4; ++j) bf[j] = *(const short8*)&Bs[buf][wn*64 + j*16 + fr][g*8];
    #pragma unroll
    for (int j = 0; j < 4; ++j)
      acc[j] = __builtin_amdgcn_mfma_f32_16x16x32_bf16(af, bf[j], acc[j], 0, 0, 0);
    buf ^= 1;
  }
  {
    rb0 = *(const uint4*)(bPt0 + 20*32);
    rb1 = *(const uint4*)(bPt1 + 20*32);
    *(uint4*)&Bs[buf][colB][qB*8] = rb0;
    *(uint4*)&Bs[buf][colB+64][qB*8] = rb1;
    if (tid < 32) {
      int row = tid, gr2 = R0 + row; if (gr2 >= BN) gr2 = BN - 1;
      int b2 = gr2 / N, n2 = gr2 - b2*N;
      const ushort16* base = xall + (size_t)n2*US + b2*SEG + 128;
      short8 v = {0,0,0,0,0,0,0,0};
      #pragma unroll
      for (int m = 0; m < MM; ++m) v[m] = (short)base[(size_t)m*mstride];
      short8 z = {0,0,0,0,0,0,0,0};
      *(short8*)&As[buf][row][0]  = v;
      *(short8*)&As[buf][row][8]  = z;
      *(short8*)&As[buf][row][16] = z;
      *(short8*)&As[buf][row][24] = z;
    }
    __syncthreads();
    short8 af = *(const short8*)&As[buf][wm*16 + fr][g*8];
    short8 bf[4];
    #pragma unroll
    for (int j = 0; j < 4; ++j) bf[j] = *(const short8*)&Bs[buf][wn*64 + j*16 + fr][g*8];
    #pragma unroll
    for (int j = 0; j < 4; ++j)
      acc[j] = __builtin_amdgcn_mfma_f32_16x16x32_bf16(af, bf[j], acc[j], 0, 0, 0);
  }
  // epilogue: GRU combine + projection partial
  #pragma unroll
  for (int q = 0; q < 4; ++q) {
    int row = R0 + wm*16 + g*4 + q;
    bool rok = row < BN;
    float pj = 0.f;
    #pragma unroll
    for (int j = 0; j < 4; ++j) {
      int o = wn*64 + j*16 + fr;
      float gv = acc[j][q] + bias[o];
      float cv = tanhf(gv);
      if (rok) {
        float uu = bf2f(ub[(size_t)row*RUNITS + o]);
        float hh = hx[(size_t)row*RUNITS + o];
        float nh = uu*hh + (1.f - uu)*cv;
        outh[(size_t)row*RUNITS + o] = nh;
        pj += nh * wpj[o];
      }
    }
    #pragma unroll
    for (int d = 1; d < 16; d <<= 1) pj += __shfl_xor(pj, d);
    if (rok && fr == 0) atomicAdd(&outy[row], pj);
  }
}

__global__ void k_inity(float* y, const float* bp, int n) {
  int i = blockIdx.x*blockDim.x + threadIdx.x;
  if (i < n) y[i] = bp[0];
}

// ---------------- launcher ----------------

extern "C" void kernel_launch(void* const* d_in, const int* in_sizes, int n_in,
                              void* d_out, int out_size, void* d_ws, size_t ws_size,
                              hipStream_t stream) {
  const float* inputs = (const float*)d_in[0];
  const float* hidden = (const float*)d_in[1];
  const int*   esrc   = (const int*)d_in[2];
  const int*   edst   = (const int*)d_in[3];
  const float* ew     = (const float*)d_in[4];
  const float* Wg     = (const float*)d_in[5];
  const float* bg     = (const float*)d_in[6];
  const float* Wc     = (const float*)d_in[7];
  const float* bc     = (const float*)d_in[8];
  const float* Wpj    = (const float*)d_in[9];
  const float* bpj    = (const float*)d_in[10];

  const int N  = in_sizes[0] / BATCH;
  const int E  = in_sizes[2];
  const int BN = BATCH * N;

  char* p = (char*)d_ws;
  auto alloc = [&](size_t bytes) -> void* {
    void* r = (void*)p;
    p += (bytes + 255) & ~(size_t)255;
    return r;
  };

  float* deg_out = (float*)alloc((size_t)4*N*sizeof(float));
  float* deg_in  = deg_out + N;
  int*   cnt_f   = (int*)(deg_out + 2*(size_t)N);
  int*   cnt_b   = cnt_f + N;
  int*   ptr_f   = (int*)alloc((size_t)(N+1)*sizeof(int));
  int*   ptr_b   = (int*)alloc((size_t)(N+1)*sizeof(int));
  int*   cur_f   = (int*)alloc((size_t)N*sizeof(int));
  int*   cur_b   = (int*)alloc((size_t)N*sizeof(int));
  int*   col_f   = (int*)alloc((size_t)E*sizeof(int));
  int*   col_b   = (int*)alloc((size_t)E*sizeof(int));
  float* val_f   = (float*)alloc((size_t)E*sizeof(float));
  float* val_b   = (float*)alloc((size_t)E*sizeof(float));
  int*   bsum    = (int*)alloc(80*sizeof(int));
  int*   bofs    = (int*)alloc(80*sizeof(int));
  ushort16* WtG  = (ushort16*)alloc((size_t)2*RUNITS*KB*sizeof(ushort16));
  ushort16* WtC  = (ushort16*)alloc((size_t)RUNITS*KB*sizeof(ushort16));
  ushort16* xall = (ushort16*)alloc((size_t)MM*N*US*sizeof(ushort16));
  ushort16* rh   = (ushort16*)alloc((size_t)BN*RUNITS*sizeof(ushort16));
  ushort16* ub   = (ushort16*)alloc((size_t)BN*RUNITS*sizeof(ushort16));

  float* out_y = (float*)d_out;
  float* out_h = out_y + BN;

  ushort16* x0 = xall;
  ushort16* x1 = xall + (size_t)1*N*US;
  ushort16* x2 = xall + (size_t)2*N*US;
  ushort16* x3 = xall + (size_t)3*N*US;
  ushort16* x4 = xall + (size_t)4*N*US;

  const int TB = 256;
  int nb = (N + 255)/256;   // = 40 for N=10000
  // prep
  k_zero_i<<<(4*N+TB-1)/TB, TB, 0, stream>>>((int*)deg_out, 4*N);
  k_deg_cnt<<<(E+TB-1)/TB, TB, 0, stream>>>(esrc, edst, ew, E, deg_out, deg_in, cnt_f, cnt_b);
  k_scansum<<<dim3(nb,2), TB, 0, stream>>>(cnt_f, cnt_b, bsum, N);
  k_scanmid<<<1, 64, 0, stream>>>(bsum, bofs, ptr_f, ptr_b, N, nb);
  k_scanapply<<<dim3(nb,2), TB, 0, stream>>>(cnt_f, cnt_b, bofs, ptr_f, cur_f, ptr_b, cur_b, N);
  k_fill<<<(E+TB-1)/TB, TB, 0, stream>>>(esrc, edst, ew, E, deg_out, deg_in,
                                         cur_f, cur_b, col_f, val_f, col_b, val_b);
  k_packw<<<(2*RUNITS*KB+TB-1)/TB, TB, 0, stream>>>(Wg, WtG, 2*RUNITS);
  k_packw<<<(RUNITS*KB+TB-1)/TB, TB, 0, stream>>>(Wc, WtC, RUNITS);
  k_inity<<<(BN+TB-1)/TB, TB, 0, stream>>>(out_y, bpj, BN);

  int sgrid = (N + 3) / 4;
  int gxg = (BN + 63) / 64;
  int gxc = (BN + 31) / 32;

  // ---- gates gconv ----
  k_build_x0<false><<<sgrid, TB, 0, stream>>>(inputs, hidden, x0, N);
  k_spmm2<false><<<2*sgrid, TB, 0, stream>>>(ptr_f, col_f, val_f, x0, x1,
                                             ptr_b, col_b, val_b, x0, x3,
                                             x0, N, sgrid, 1.f, 0.f);
  k_spmm2<true ><<<2*sgrid, TB, 0, stream>>>(ptr_f, col_f, val_f, x1, x2,
                                             ptr_b, col_b, val_b, x3, x4,
                                             x0, N, sgrid, 2.f, -1.f);
  k_gemm_g<<<dim3(gxg, 2), TB, 0, stream>>>(xall, WtG, bg, hidden, rh, ub, N, BN);

  // ---- candidate gconv ----
  k_build_x0<true><<<sgrid, TB, 0, stream>>>(inputs, rh, x0, N);
  k_spmm2<false><<<2*sgrid, TB, 0, stream>>>(ptr_f, col_f, val_f, x0, x1,
                                             ptr_b, col_b, val_b, x0, x3,
                                             x0, N, sgrid, 1.f, 0.f);
  k_spmm2<true ><<<2*sgrid, TB, 0, stream>>>(ptr_f, col_f, val_f, x1, x2,
                                             ptr_b, col_b, val_b, x3, x4,
                                             x0, N, sgrid, 2.f, -1.f);
  k_gemm_c<<<dim3(gxc, 1), TB, 0, stream>>>(xall, WtC, bc, hidden, ub,
                                            out_h, out_y, Wpj, N, BN);
}